// Round 1
// baseline (3324.069 us; speedup 1.0000x reference)
//
#include <hip/hip_runtime.h>
#include <math.h>

// Problem constants (from reference)
constexpr int NN   = 50000;
constexpr int NE   = 800000;
constexpr int NE2  = NE + NN;     // GAT adds self-loops
constexpr int NREL = 4;

// ---------------------------------------------------------------------------
// counts: deg[dst] (for SAGE mean), cntrel[dst*4+etype] (for RGCN per-rel mean)
__global__ void k_counts(const int* __restrict__ src, const int* __restrict__ dst,
                         const int* __restrict__ et, int* deg, int* cntrel) {
  int e = blockIdx.x * blockDim.x + threadIdx.x;
  if (e < NE) {
    int d = dst[e];
    atomicAdd(&deg[d], 1);
    atomicAdd(&cntrel[d * NREL + et[e]], 1);
  }
}

// ---------------------------------------------------------------------------
// segment-sum gather: acc[dst][c] += x[src][c], flattened over (edge, channel)
template<int CSH>   // log2(C)
__global__ void k_gather_sum(const float* __restrict__ xin, const int* __restrict__ src,
                             const int* __restrict__ dst, float* __restrict__ acc) {
  const long total = (long)NE << CSH;
  const long stride = (long)gridDim.x * blockDim.x;
  for (long idx = (long)blockIdx.x * blockDim.x + threadIdx.x; idx < total; idx += stride) {
    int e = (int)(idx >> CSH);
    int c = (int)(idx & ((1 << CSH) - 1));
    int s = src[e], d = dst[e];
    atomicAdd(&acc[((size_t)d << CSH) + c], xin[((size_t)s << CSH) + c]);
  }
}

// mean = sum / max(count,1)
template<int CSH>
__global__ void k_scale(float* acc, const int* __restrict__ deg) {
  long idx = (long)blockIdx.x * blockDim.x + threadIdx.x;
  if (idx >= ((long)NN << CSH)) return;
  int node = (int)(idx >> CSH);
  int dv = deg[node];
  if (dv > 1) acc[idx] *= (1.0f / (float)dv);
}

// ---------------------------------------------------------------------------
// Generic fp32 GEMM: C = [A0|A1|A2] @ [B0;B1;B2] (+bias)(+relu)
// A_i: M x K_i row-major, B_i: K_i x Nc row-major. K_i % 16 == 0 required.
constexpr int BM = 128, BN = 64, BK = 16;
constexpr int ASTR = BM + 4;   // 132 (pad for banks; 16B-aligned rows)
constexpr int BSTR = BN + 4;   // 68

__global__ __launch_bounds__(256)
void k_gemm(const float* __restrict__ A0, const float* __restrict__ B0, int K0,
            const float* __restrict__ A1p, const float* __restrict__ B1p, int K1,
            const float* __restrict__ A2p, const float* __restrict__ B2p, int K2,
            const float* __restrict__ bias, float* __restrict__ Cout,
            int M, int Nc, int do_relu)
{
  __shared__ float As[BK * ASTR];
  __shared__ float Bs[BK * BSTR];
  const int tid  = threadIdx.x;
  const int row0 = blockIdx.y * BM;
  const int col0 = blockIdx.x * BN;
  const int tm = tid >> 4;        // 0..15 -> 8 rows
  const int tn = tid & 15;        // 0..15 -> 4 cols

  float acc[8][4];
#pragma unroll
  for (int i = 0; i < 8; ++i)
#pragma unroll
    for (int j = 0; j < 4; ++j) acc[i][j] = 0.0f;

  const int a_r = tid >> 1;        // 0..127
  const int a_k = (tid & 1) * 8;   // 0 or 8
  const int b_k = tid >> 4;        // 0..15
  const int b_c = (tid & 15) * 4;  // 0..60

  const float* Aarr[3] = {A0, A1p, A2p};
  const float* Barr[3] = {B0, B1p, B2p};
  const int    Karr[3] = {K0, K1, K2};

  for (int p = 0; p < 3; ++p) {
    const float* A = Aarr[p];
    const float* B = Barr[p];
    const int K = Karr[p];
    if (K == 0) continue;
    const bool arow_ok = (row0 + a_r) < M;
    const float* Arow = arow_ok ? (A + (size_t)(row0 + a_r) * K + a_k) : nullptr;
    for (int kt = 0; kt < K; kt += BK) {
      float4 av0, av1, bv;
      if (arow_ok) {
        av0 = *(const float4*)(Arow + kt);
        av1 = *(const float4*)(Arow + kt + 4);
      } else {
        av0 = make_float4(0,0,0,0); av1 = make_float4(0,0,0,0);
      }
      if (col0 + b_c < Nc)
        bv = *(const float4*)(B + (size_t)(kt + b_k) * Nc + col0 + b_c);
      else
        bv = make_float4(0,0,0,0);

      __syncthreads();   // previous tile's compute done before overwrite
      As[(a_k+0)*ASTR + a_r] = av0.x;
      As[(a_k+1)*ASTR + a_r] = av0.y;
      As[(a_k+2)*ASTR + a_r] = av0.z;
      As[(a_k+3)*ASTR + a_r] = av0.w;
      As[(a_k+4)*ASTR + a_r] = av1.x;
      As[(a_k+5)*ASTR + a_r] = av1.y;
      As[(a_k+6)*ASTR + a_r] = av1.z;
      As[(a_k+7)*ASTR + a_r] = av1.w;
      *(float4*)&Bs[b_k * BSTR + b_c] = bv;
      __syncthreads();

#pragma unroll
      for (int kk = 0; kk < BK; ++kk) {
        float4 a0 = *(const float4*)&As[kk*ASTR + tm*8];
        float4 a1 = *(const float4*)&As[kk*ASTR + tm*8 + 4];
        float4 b  = *(const float4*)&Bs[kk*BSTR + tn*4];
        float av[8] = {a0.x,a0.y,a0.z,a0.w,a1.x,a1.y,a1.z,a1.w};
        float bw[4] = {b.x,b.y,b.z,b.w};
#pragma unroll
        for (int i = 0; i < 8; ++i)
#pragma unroll
          for (int j = 0; j < 4; ++j)
            acc[i][j] = fmaf(av[i], bw[j], acc[i][j]);
      }
    }
  }

  float4 bb = make_float4(0,0,0,0);
  if (bias && (col0 + tn*4 < Nc)) bb = *(const float4*)(bias + col0 + tn*4);
#pragma unroll
  for (int i = 0; i < 8; ++i) {
    int r = row0 + tm*8 + i;
    if (r < M && (col0 + tn*4) < Nc) {
      float4 v = make_float4(acc[i][0]+bb.x, acc[i][1]+bb.y, acc[i][2]+bb.z, acc[i][3]+bb.w);
      if (do_relu) {
        v.x = fmaxf(v.x, 0.f); v.y = fmaxf(v.y, 0.f);
        v.z = fmaxf(v.z, 0.f); v.w = fmaxf(v.w, 0.f);
      }
      *(float4*)(Cout + (size_t)r * Nc + col0 + tn*4) = v;
    }
  }
}

// ---------------------------------------------------------------------------
// GAT pieces
__device__ inline unsigned f2key(float f) {
  unsigned b = __float_as_uint(f);
  return (b & 0x80000000u) ? ~b : (b | 0x80000000u);
}
__device__ inline float key2f(unsigned k) {
  unsigned b = (k & 0x80000000u) ? (k & 0x7FFFFFFFu) : ~k;
  return __uint_as_float(b);
}

// per (node,head) attention logits: al = sum_c h[n,head,c]*att[head,c]
__global__ void k_gat_al(const float* __restrict__ h, const float* __restrict__ att_s,
                         const float* __restrict__ att_d, float* al_s, float* al_d) {
  int nh = blockIdx.x;           // node*2 + head
  int node = nh >> 1, head = nh & 1;
  int lane = threadIdx.x;        // 64
  const float* hp = h + (size_t)node * 512 + head * 256;
  const float* as = att_s + head * 256;
  const float* ad = att_d + head * 256;
  float s1 = 0.f, s2 = 0.f;
  for (int c = lane; c < 256; c += 64) {
    float v = hp[c];
    s1 += v * as[c];
    s2 += v * ad[c];
  }
  for (int off = 32; off; off >>= 1) { s1 += __shfl_down(s1, off); s2 += __shfl_down(s2, off); }
  if (lane == 0) { al_s[nh] = s1; al_d[nh] = s2; }
}

__global__ void k_gat_max(const int* __restrict__ src, const int* __restrict__ dst,
                          const float* __restrict__ al_s, const float* __restrict__ al_d,
                          unsigned* mkey) {
  int e = blockIdx.x * blockDim.x + threadIdx.x;
  if (e >= NE2) return;
  int s, d;
  if (e < NE) { s = src[e]; d = dst[e]; } else { s = d = e - NE; }
#pragma unroll
  for (int hd = 0; hd < 2; ++hd) {
    float v = al_s[s*2 + hd] + al_d[d*2 + hd];
    v = v > 0.f ? v : 0.2f * v;           // leaky_relu 0.2
    atomicMax(&mkey[d*2 + hd], f2key(v));
  }
}

__global__ void k_gat_exp(const int* __restrict__ src, const int* __restrict__ dst,
                          const float* __restrict__ al_s, const float* __restrict__ al_d,
                          const unsigned* __restrict__ mkey, float* ex, float* den) {
  int e = blockIdx.x * blockDim.x + threadIdx.x;
  if (e >= NE2) return;
  int s, d;
  if (e < NE) { s = src[e]; d = dst[e]; } else { s = d = e - NE; }
#pragma unroll
  for (int hd = 0; hd < 2; ++hd) {
    float v = al_s[s*2 + hd] + al_d[d*2 + hd];
    v = v > 0.f ? v : 0.2f * v;
    float m = key2f(mkey[d*2 + hd]);
    float xv = __expf(v - m);
    ex[(size_t)e*2 + hd] = xv;
    atomicAdd(&den[d*2 + hd], xv);
  }
}

// ex -> alpha (normalize by den)
__global__ void k_gat_alpha(const int* __restrict__ dst, float* ex, const float* __restrict__ den) {
  int idx = blockIdx.x * blockDim.x + threadIdx.x;   // e*2+hd
  if (idx >= NE2*2) return;
  int e = idx >> 1, hd = idx & 1;
  int d = (e < NE) ? dst[e] : (e - NE);
  ex[idx] = ex[idx] / fmaxf(den[d*2 + hd], 1e-16f);
}

// acc[dst][c] += 0.5*(a0*h[src,0,c] + a1*h[src,1,c])  (head-mean folded in)
__global__ void k_gat_agg(const int* __restrict__ src, const int* __restrict__ dst,
                          const float* __restrict__ h, const float* __restrict__ alpha,
                          float* __restrict__ acc) {
  const long total = (long)NE2 << 8;
  const long stride = (long)gridDim.x * blockDim.x;
  for (long idx = (long)blockIdx.x * blockDim.x + threadIdx.x; idx < total; idx += stride) {
    int e = (int)(idx >> 8);
    int c = (int)(idx & 255);
    int s, d;
    if (e < NE) { s = src[e]; d = dst[e]; } else { s = d = e - NE; }
    float a0 = alpha[(size_t)e*2];
    float a1 = alpha[(size_t)e*2 + 1];
    float v = 0.5f * (a0 * h[((size_t)s << 9) + c] + a1 * h[((size_t)s << 9) + 256 + c]);
    atomicAdd(&acc[((size_t)d << 8) + c], v);
  }
}

__global__ void k_gat_fin(float* acc, const float* __restrict__ b) {
  long idx = (long)blockIdx.x * blockDim.x + threadIdx.x;
  if (idx < (long)NN * 256) {
    int c = (int)(idx & 255);
    acc[idx] = fmaxf(acc[idx] + b[c], 0.f);
  }
}

// ---------------------------------------------------------------------------
// RGCN: per-edge 1/cnt(dst,rel), then out[dst][c] += xt[rel][src][c] * einv[e]
__global__ void k_einv(const int* __restrict__ dst, const int* __restrict__ et,
                       const int* __restrict__ cntrel, float* __restrict__ einv) {
  int e = blockIdx.x * blockDim.x + threadIdx.x;
  if (e < NE) einv[e] = 1.0f / (float)cntrel[dst[e]*NREL + et[e]];
}

__global__ void k_rgcn_agg(const int* __restrict__ src, const int* __restrict__ dst,
                           const int* __restrict__ et, const float* __restrict__ xt,
                           const float* __restrict__ einv, float* __restrict__ outp) {
  const long total = (long)NE << 7;
  const long stride = (long)gridDim.x * blockDim.x;
  for (long idx = (long)blockIdx.x * blockDim.x + threadIdx.x; idx < total; idx += stride) {
    int e = (int)(idx >> 7);
    int c = (int)(idx & 127);
    int s = src[e], d = dst[e], r = et[e];
    float v = xt[(((size_t)r * NN + s) << 7) + c] * einv[e];
    atomicAdd(&outp[((size_t)d << 7) + c], v);
  }
}

// ---------------------------------------------------------------------------
// row L2 normalize (in place), one wave per node, 128 cols
__global__ void k_norm(float* __restrict__ out) {
  int gw = (int)(((long)blockIdx.x * blockDim.x + threadIdx.x) >> 6);
  int lane = threadIdx.x & 63;
  if (gw >= NN) return;
  float2* row = (float2*)(out + (size_t)gw * 128);
  float2 v = row[lane];
  float ss = v.x*v.x + v.y*v.y;
  for (int off = 32; off; off >>= 1) ss += __shfl_down(ss, off);
  ss = __shfl(ss, 0);
  float inv = 1.0f / fmaxf(sqrtf(ss), 1e-12f);
  row[lane] = make_float2(v.x*inv, v.y*inv);
}

// ---------------------------------------------------------------------------
extern "C" void kernel_launch(void* const* d_in, const int* in_sizes, int n_in,
                              void* d_out, int out_size, void* d_ws, size_t ws_size,
                              hipStream_t stream)
{
  const float* x     = (const float*)d_in[0];
  const int*   ei    = (const int*)d_in[1];
  const int*   etype = (const int*)d_in[2];
  const float* s1Wl  = (const float*)d_in[3];
  const float* s1Wr  = (const float*)d_in[4];
  const float* s1b   = (const float*)d_in[5];
  const float* s2Wl  = (const float*)d_in[6];
  const float* s2Wr  = (const float*)d_in[7];
  const float* s2b   = (const float*)d_in[8];
  const float* gatW  = (const float*)d_in[9];
  const float* att_s = (const float*)d_in[10];
  const float* att_d = (const float*)d_in[11];
  const float* gatb  = (const float*)d_in[12];
  const float* Wrel  = (const float*)d_in[13];
  const float* Wroot = (const float*)d_in[14];
  const float* rgcnb = (const float*)d_in[15];
  const float* fW    = (const float*)d_in[16];
  const float* fb    = (const float*)d_in[17];
  float* out = (float*)d_out;

  const int* src = ei;
  const int* dst = ei + NE;

  char* ws = (char*)d_ws;
  size_t off = 0;
  auto alloc = [&](size_t bytes) -> void* {
    void* p = ws + off;
    off = (off + bytes + 255) & ~(size_t)255;
    return p;
  };
  int*      deg    = (int*)alloc((size_t)NN * 4);
  int*      cntrel = (int*)alloc((size_t)NN * NREL * 4);
  float*    al_s   = (float*)alloc((size_t)NN * 2 * 4);
  float*    al_d   = (float*)alloc((size_t)NN * 2 * 4);
  unsigned* mkey   = (unsigned*)alloc((size_t)NN * 2 * 4);
  float*    den    = (float*)alloc((size_t)NN * 2 * 4);
  float*    ex     = (float*)alloc((size_t)NE2 * 2 * 4);
  float*    einv   = (float*)alloc((size_t)NE * 4);
  float*    S1     = (float*)alloc((size_t)NN * 512 * 4);  // A1 / A2 / h / xt
  float*    P1     = (float*)alloc((size_t)NN * 256 * 4);  // x_sage
  float*    P2     = (float*)alloc((size_t)NN * 256 * 4);  // x1, then x_gat
  float*    P3     = (float*)alloc((size_t)NN * 128 * 4);  // x_rgcn
  (void)ws_size; (void)in_sizes; (void)n_in; (void)out_size;

  const int GRID_E = 16384;

  // ---- counts
  hipMemsetAsync(deg, 0, (size_t)NN * 4, stream);
  hipMemsetAsync(cntrel, 0, (size_t)NN * NREL * 4, stream);
  k_counts<<<(NE + 255) / 256, 256, 0, stream>>>(src, dst, etype, deg, cntrel);

  // ---- SAGE1: A1 = segmean(x) ; x1 = relu(A1@Wl + x@Wr + b) -> P2
  hipMemsetAsync(S1, 0, (size_t)NN * 128 * 4, stream);
  k_gather_sum<7><<<GRID_E, 256, 0, stream>>>(x, src, dst, S1);
  k_scale<7><<<((NN * 128) + 255) / 256, 256, 0, stream>>>(S1, deg);
  {
    dim3 g(256 / BN, (NN + BM - 1) / BM);
    k_gemm<<<g, 256, 0, stream>>>(S1, s1Wl, 128, x, s1Wr, 128, nullptr, nullptr, 0,
                                  s1b, P2, NN, 256, 1);
  }

  // ---- SAGE2: A2 = segmean(x1) ; x_sage = relu(A2@Wl + x1@Wr + b) -> P1
  hipMemsetAsync(S1, 0, (size_t)NN * 256 * 4, stream);
  k_gather_sum<8><<<GRID_E, 256, 0, stream>>>(P2, src, dst, S1);
  k_scale<8><<<((NN * 256) + 255) / 256, 256, 0, stream>>>(S1, deg);
  {
    dim3 g(256 / BN, (NN + BM - 1) / BM);
    k_gemm<<<g, 256, 0, stream>>>(S1, s2Wl, 256, P2, s2Wr, 256, nullptr, nullptr, 0,
                                  s2b, P1, NN, 256, 1);
  }

  // ---- GAT: h = x_sage @ W -> S1 (N x 512)
  {
    dim3 g(512 / BN, (NN + BM - 1) / BM);
    k_gemm<<<g, 256, 0, stream>>>(P1, gatW, 256, nullptr, nullptr, 0, nullptr, nullptr, 0,
                                  nullptr, S1, NN, 512, 0);
  }
  k_gat_al<<<NN * 2, 64, 0, stream>>>(S1, att_s, att_d, al_s, al_d);
  hipMemsetAsync(mkey, 0, (size_t)NN * 2 * 4, stream);
  hipMemsetAsync(den, 0, (size_t)NN * 2 * 4, stream);
  k_gat_max<<<(NE2 + 255) / 256, 256, 0, stream>>>(src, dst, al_s, al_d, mkey);
  k_gat_exp<<<(NE2 + 255) / 256, 256, 0, stream>>>(src, dst, al_s, al_d, mkey, ex, den);
  k_gat_alpha<<<(NE2 * 2 + 255) / 256, 256, 0, stream>>>(dst, ex, den);
  hipMemsetAsync(P2, 0, (size_t)NN * 256 * 4, stream);   // x1 dead; reuse for gat accum
  k_gat_agg<<<GRID_E, 256, 0, stream>>>(src, dst, S1, ex, P2);
  k_gat_fin<<<((long)NN * 256 + 255) / 256, 256, 0, stream>>>(P2, gatb);

  // ---- RGCN: xt[r] = x_gat @ Wrel[r] -> S1 (4 x N x 128); P3 = x_gat@Wroot + b
  for (int r = 0; r < NREL; ++r) {
    dim3 g(128 / BN, (NN + BM - 1) / BM);
    k_gemm<<<g, 256, 0, stream>>>(P2, Wrel + (size_t)r * 256 * 128, 256,
                                  nullptr, nullptr, 0, nullptr, nullptr, 0,
                                  nullptr, S1 + (size_t)r * NN * 128, NN, 128, 0);
  }
  {
    dim3 g(128 / BN, (NN + BM - 1) / BM);
    k_gemm<<<g, 256, 0, stream>>>(P2, Wroot, 256, nullptr, nullptr, 0, nullptr, nullptr, 0,
                                  rgcnb, P3, NN, 128, 0);
  }
  k_einv<<<(NE + 255) / 256, 256, 0, stream>>>(dst, etype, cntrel, einv);
  k_rgcn_agg<<<GRID_E, 256, 0, stream>>>(src, dst, etype, S1, einv, P3);

  // ---- fusion: out = [x_sage | x_gat | x_rgcn] @ fW + fb, then L2 normalize
  {
    dim3 g(128 / BN, (NN + BM - 1) / BM);
    k_gemm<<<g, 256, 0, stream>>>(P1, fW, 256,
                                  P2, fW + 256 * 128, 256,
                                  P3, fW + 512 * 128, 128,
                                  fb, out, NN, 128, 0);
  }
  k_norm<<<(NN + 3) / 4, 256, 0, stream>>>(out);
}

// Round 2
// 1813.622 us; speedup vs baseline: 1.8328x; 1.8328x over previous
//
#include <hip/hip_runtime.h>
#include <math.h>

constexpr int NN   = 50000;
constexpr int NE   = 800000;
constexpr int NE2  = NE + NN;     // GAT adds self-loops
constexpr int NREL = 4;
constexpr int NB   = (NN + 255) / 256;   // scan blocks = 196

// ---------------------------------------------------------------------------
// counts: deg[dst], cntrel[dst*4+etype]
__global__ void k_counts(const int* __restrict__ src, const int* __restrict__ dst,
                         const int* __restrict__ et, int* deg, int* cntrel) {
  int e = blockIdx.x * blockDim.x + threadIdx.x;
  if (e < NE) {
    int d = dst[e];
    atomicAdd(&deg[d], 1);
    atomicAdd(&cntrel[d * NREL + et[e]], 1);
  }
}

// ---------------------------------------------------------------------------
// exclusive scan of deg -> rowptr (3 tiny kernels)
__global__ void k_scan1(const int* __restrict__ deg, int* bsum) {
  __shared__ int sm[256];
  int i = blockIdx.x * 256 + threadIdx.x;
  sm[threadIdx.x] = (i < NN) ? deg[i] : 0;
  __syncthreads();
  for (int s = 128; s; s >>= 1) {
    if (threadIdx.x < s) sm[threadIdx.x] += sm[threadIdx.x + s];
    __syncthreads();
  }
  if (threadIdx.x == 0) bsum[blockIdx.x] = sm[0];
}
__global__ void k_scan2(const int* __restrict__ bsum, int* boff, int* rowptr) {
  if (threadIdx.x == 0 && blockIdx.x == 0) {
    int acc = 0;
    for (int b = 0; b < NB; ++b) { boff[b] = acc; acc += bsum[b]; }
    rowptr[NN] = NE;
  }
}
__global__ void k_scan3(const int* __restrict__ deg, const int* __restrict__ boff,
                        int* rowptr) {
  __shared__ int sm[256];
  int i = blockIdx.x * 256 + threadIdx.x;
  int v = (i < NN) ? deg[i] : 0;
  sm[threadIdx.x] = v;
  __syncthreads();
  for (int s = 1; s < 256; s <<= 1) {
    int t = (threadIdx.x >= s) ? sm[threadIdx.x - s] : 0;
    __syncthreads();
    sm[threadIdx.x] += t;
    __syncthreads();
  }
  if (i < NN) rowptr[i] = boff[blockIdx.x] + sm[threadIdx.x] - v;  // exclusive
}

// fill CSR: srcs/ets/perm grouped by dst
__global__ void k_fill(const int* __restrict__ src, const int* __restrict__ dst,
                       const int* __restrict__ et, const int* __restrict__ rowptr,
                       int* cursor, int* srcs, int* ets, int* perm) {
  int e = blockIdx.x * blockDim.x + threadIdx.x;
  if (e >= NE) return;
  int d = dst[e];
  int pos = rowptr[d] + atomicAdd(&cursor[d], 1);
  srcs[pos] = src[e];
  ets[pos]  = et[e];
  perm[pos] = e;
}

// ---------------------------------------------------------------------------
// CSR mean aggregation: one wave per dst node, C = 1<<CSH channels
template<int CSH>
__global__ void k_csr_mean(const float* __restrict__ xin, const int* __restrict__ rowptr,
                           const int* __restrict__ srcs, float* __restrict__ outp) {
  int node = blockIdx.x * 4 + (threadIdx.x >> 6);
  int lane = threadIdx.x & 63;
  if (node >= NN) return;
  int p0 = rowptr[node], p1 = rowptr[node + 1];
  constexpr int R = (1 << CSH) / 64;
  float acc[R] = {};
  int p = p0;
  int s = (p < p1) ? srcs[p] : 0;
  while (p < p1) {
    int sn = (p + 1 < p1) ? srcs[p + 1] : 0;
    const float* row = xin + ((size_t)s << CSH);
#pragma unroll
    for (int j = 0; j < R; ++j) acc[j] += row[lane + 64 * j];
    s = sn; ++p;
  }
  float inv = (p1 > p0) ? 1.0f / (float)(p1 - p0) : 0.0f;
  float* orow = outp + ((size_t)node << CSH);
#pragma unroll
  for (int j = 0; j < R; ++j) orow[lane + 64 * j] = acc[j] * inv;
}

// ---------------------------------------------------------------------------
// fp32 GEMM: C = [A0|A1|A2] @ [B0;B1;B2] (+bias)(+relu). K_i%16==0, Nc%128==0.
constexpr int BM = 128, BN = 128, BK = 16;
constexpr int ASTR = BM + 4;   // 132
constexpr int BSTR = BN + 4;   // 132

__global__ __launch_bounds__(256)
void k_gemm(const float* __restrict__ A0, const float* __restrict__ B0, int K0,
            const float* __restrict__ A1p, const float* __restrict__ B1p, int K1,
            const float* __restrict__ A2p, const float* __restrict__ B2p, int K2,
            const float* __restrict__ bias, float* __restrict__ Cout,
            int M, int Nc, int do_relu)
{
  __shared__ float As[BK * ASTR];
  __shared__ float Bs[BK * BSTR];
  const int tid  = threadIdx.x;
  const int row0 = blockIdx.y * BM;
  const int col0 = blockIdx.x * BN;
  const int tm = tid >> 4;         // 0..15 -> 8 rows
  const int tn = tid & 15;         // 0..15 -> 8 cols

  float acc[8][8];
#pragma unroll
  for (int i = 0; i < 8; ++i)
#pragma unroll
    for (int j = 0; j < 8; ++j) acc[i][j] = 0.0f;

  const int a_r = tid >> 1;        // 0..127
  const int a_k = (tid & 1) * 8;   // 0 or 8
  const int b_k = tid >> 4;        // 0..15
  const int b_c = (tid & 15) * 8;  // 0..120

  const float* Aarr[3] = {A0, A1p, A2p};
  const float* Barr[3] = {B0, B1p, B2p};
  const int    Karr[3] = {K0, K1, K2};

  for (int p = 0; p < 3; ++p) {
    const float* A = Aarr[p];
    const float* B = Barr[p];
    const int K = Karr[p];
    if (K == 0) continue;
    const bool arow_ok = (row0 + a_r) < M;
    const float* Arow = arow_ok ? (A + (size_t)(row0 + a_r) * K + a_k) : nullptr;
    const float* Bcol = B + col0 + b_c;
    for (int kt = 0; kt < K; kt += BK) {
      float4 av0, av1, bv0, bv1;
      if (arow_ok) {
        av0 = *(const float4*)(Arow + kt);
        av1 = *(const float4*)(Arow + kt + 4);
      } else {
        av0 = make_float4(0,0,0,0); av1 = make_float4(0,0,0,0);
      }
      bv0 = *(const float4*)(Bcol + (size_t)(kt + b_k) * Nc);
      bv1 = *(const float4*)(Bcol + (size_t)(kt + b_k) * Nc + 4);

      __syncthreads();
      As[(a_k+0)*ASTR + a_r] = av0.x;
      As[(a_k+1)*ASTR + a_r] = av0.y;
      As[(a_k+2)*ASTR + a_r] = av0.z;
      As[(a_k+3)*ASTR + a_r] = av0.w;
      As[(a_k+4)*ASTR + a_r] = av1.x;
      As[(a_k+5)*ASTR + a_r] = av1.y;
      As[(a_k+6)*ASTR + a_r] = av1.z;
      As[(a_k+7)*ASTR + a_r] = av1.w;
      *(float4*)&Bs[b_k * BSTR + b_c] = bv0;
      *(float4*)&Bs[b_k * BSTR + b_c + 4] = bv1;
      __syncthreads();

#pragma unroll
      for (int kk = 0; kk < BK; ++kk) {
        float4 a0 = *(const float4*)&As[kk*ASTR + tm*8];
        float4 a1 = *(const float4*)&As[kk*ASTR + tm*8 + 4];
        float4 b0 = *(const float4*)&Bs[kk*BSTR + tn*8];
        float4 b1 = *(const float4*)&Bs[kk*BSTR + tn*8 + 4];
        float av[8] = {a0.x,a0.y,a0.z,a0.w,a1.x,a1.y,a1.z,a1.w};
        float bw[8] = {b0.x,b0.y,b0.z,b0.w,b1.x,b1.y,b1.z,b1.w};
#pragma unroll
        for (int i = 0; i < 8; ++i)
#pragma unroll
          for (int j = 0; j < 8; ++j)
            acc[i][j] = fmaf(av[i], bw[j], acc[i][j]);
      }
    }
  }

  float4 bb0 = make_float4(0,0,0,0), bb1 = make_float4(0,0,0,0);
  if (bias) {
    bb0 = *(const float4*)(bias + col0 + tn*8);
    bb1 = *(const float4*)(bias + col0 + tn*8 + 4);
  }
#pragma unroll
  for (int i = 0; i < 8; ++i) {
    int r = row0 + tm*8 + i;
    if (r < M) {
      float4 v0 = make_float4(acc[i][0]+bb0.x, acc[i][1]+bb0.y, acc[i][2]+bb0.z, acc[i][3]+bb0.w);
      float4 v1 = make_float4(acc[i][4]+bb1.x, acc[i][5]+bb1.y, acc[i][6]+bb1.z, acc[i][7]+bb1.w);
      if (do_relu) {
        v0.x=fmaxf(v0.x,0.f); v0.y=fmaxf(v0.y,0.f); v0.z=fmaxf(v0.z,0.f); v0.w=fmaxf(v0.w,0.f);
        v1.x=fmaxf(v1.x,0.f); v1.y=fmaxf(v1.y,0.f); v1.z=fmaxf(v1.z,0.f); v1.w=fmaxf(v1.w,0.f);
      }
      *(float4*)(Cout + (size_t)r * Nc + col0 + tn*8) = v0;
      *(float4*)(Cout + (size_t)r * Nc + col0 + tn*8 + 4) = v1;
    }
  }
}

// ---------------------------------------------------------------------------
// GAT pieces
__device__ inline unsigned f2key(float f) {
  unsigned b = __float_as_uint(f);
  return (b & 0x80000000u) ? ~b : (b | 0x80000000u);
}
__device__ inline float key2f(unsigned k) {
  unsigned b = (k & 0x80000000u) ? (k & 0x7FFFFFFFu) : ~k;
  return __uint_as_float(b);
}

__global__ void k_gat_al(const float* __restrict__ h, const float* __restrict__ att_s,
                         const float* __restrict__ att_d, float* al_s, float* al_d) {
  int nh = blockIdx.x;           // node*2 + head
  int node = nh >> 1, head = nh & 1;
  int lane = threadIdx.x;
  const float* hp = h + (size_t)node * 512 + head * 256;
  const float* as = att_s + head * 256;
  const float* ad = att_d + head * 256;
  float s1 = 0.f, s2 = 0.f;
  for (int c = lane; c < 256; c += 64) {
    float v = hp[c];
    s1 += v * as[c];
    s2 += v * ad[c];
  }
  for (int off = 32; off; off >>= 1) { s1 += __shfl_down(s1, off); s2 += __shfl_down(s2, off); }
  if (lane == 0) { al_s[nh] = s1; al_d[nh] = s2; }
}

__global__ void k_gat_max(const int* __restrict__ src, const int* __restrict__ dst,
                          const float* __restrict__ al_s, const float* __restrict__ al_d,
                          unsigned* mkey) {
  int e = blockIdx.x * blockDim.x + threadIdx.x;
  if (e >= NE2) return;
  int s, d;
  if (e < NE) { s = src[e]; d = dst[e]; } else { s = d = e - NE; }
#pragma unroll
  for (int hd = 0; hd < 2; ++hd) {
    float v = al_s[s*2 + hd] + al_d[d*2 + hd];
    v = v > 0.f ? v : 0.2f * v;
    atomicMax(&mkey[d*2 + hd], f2key(v));
  }
}

__global__ void k_gat_exp(const int* __restrict__ src, const int* __restrict__ dst,
                          const float* __restrict__ al_s, const float* __restrict__ al_d,
                          const unsigned* __restrict__ mkey, float* ex, float* den) {
  int e = blockIdx.x * blockDim.x + threadIdx.x;
  if (e >= NE2) return;
  int s, d;
  if (e < NE) { s = src[e]; d = dst[e]; } else { s = d = e - NE; }
#pragma unroll
  for (int hd = 0; hd < 2; ++hd) {
    float v = al_s[s*2 + hd] + al_d[d*2 + hd];
    v = v > 0.f ? v : 0.2f * v;
    float m = key2f(mkey[d*2 + hd]);
    float xv = __expf(v - m);
    ex[(size_t)e*2 + hd] = xv;
    atomicAdd(&den[d*2 + hd], xv);
  }
}

// CSR GAT aggregation: one wave per dst node; head-mean, bias, relu folded in
__global__ void k_gat_csr(const float* __restrict__ h, const int* __restrict__ rowptr,
                          const int* __restrict__ srcs, const int* __restrict__ perm,
                          const float* __restrict__ ex, const float* __restrict__ den,
                          const float* __restrict__ gatb, float* __restrict__ outp) {
  int node = blockIdx.x * 4 + (threadIdx.x >> 6);
  int lane = threadIdx.x & 63;
  if (node >= NN) return;
  int p0 = rowptr[node], p1 = rowptr[node + 1];
  float d0 = 1.0f / fmaxf(den[node*2 + 0], 1e-16f);
  float d1 = 1.0f / fmaxf(den[node*2 + 1], 1e-16f);
  float acc[4];
  {  // self loop
    float a0 = ex[(size_t)(NE + node)*2]     * d0;
    float a1 = ex[(size_t)(NE + node)*2 + 1] * d1;
    const float* row = h + ((size_t)node << 9);
#pragma unroll
    for (int j = 0; j < 4; ++j)
      acc[j] = a0 * row[lane + 64*j] + a1 * row[256 + lane + 64*j];
  }
  int p = p0;
  int s = 0, e = 0;
  if (p < p1) { s = srcs[p]; e = perm[p]; }
  while (p < p1) {
    int sn = 0, en = 0;
    if (p + 1 < p1) { sn = srcs[p+1]; en = perm[p+1]; }
    float a0 = ex[(size_t)e*2]     * d0;
    float a1 = ex[(size_t)e*2 + 1] * d1;
    const float* row = h + ((size_t)s << 9);
#pragma unroll
    for (int j = 0; j < 4; ++j)
      acc[j] += a0 * row[lane + 64*j] + a1 * row[256 + lane + 64*j];
    s = sn; e = en; ++p;
  }
  float* orow = outp + ((size_t)node << 8);
#pragma unroll
  for (int j = 0; j < 4; ++j)
    orow[lane + 64*j] = fmaxf(0.5f * acc[j] + gatb[lane + 64*j], 0.f);
}

// ---------------------------------------------------------------------------
// CSR RGCN aggregation: adds into P3 (= x_gat@Wroot + b, precomputed)
__global__ void k_rgcn_csr(const float* __restrict__ xt, const int* __restrict__ rowptr,
                           const int* __restrict__ srcs, const int* __restrict__ ets,
                           const int* __restrict__ cntrel, float* __restrict__ outp) {
  int node = blockIdx.x * 4 + (threadIdx.x >> 6);
  int lane = threadIdx.x & 63;
  if (node >= NN) return;
  int p0 = rowptr[node], p1 = rowptr[node + 1];
  float inv[NREL];
#pragma unroll
  for (int r = 0; r < NREL; ++r) {
    int c = cntrel[node*NREL + r];
    inv[r] = c ? 1.0f / (float)c : 0.0f;
  }
  float acc0 = 0.f, acc1 = 0.f;
  int p = p0;
  int s = 0, r = 0;
  if (p < p1) { s = srcs[p]; r = ets[p]; }
  while (p < p1) {
    int sn = 0, rn = 0;
    if (p + 1 < p1) { sn = srcs[p+1]; rn = ets[p+1]; }
    const float* row = xt + (((size_t)r * NN + s) << 7);
    float w = inv[r];
    acc0 += row[lane] * w;
    acc1 += row[lane + 64] * w;
    s = sn; r = rn; ++p;
  }
  float* orow = outp + ((size_t)node << 7);
  orow[lane]      += acc0;
  orow[lane + 64] += acc1;
}

// ---------------------------------------------------------------------------
// row L2 normalize
__global__ void k_norm(float* __restrict__ out) {
  int gw = (int)(((long)blockIdx.x * blockDim.x + threadIdx.x) >> 6);
  int lane = threadIdx.x & 63;
  if (gw >= NN) return;
  float2* row = (float2*)(out + (size_t)gw * 128);
  float2 v = row[lane];
  float ss = v.x*v.x + v.y*v.y;
  for (int off = 32; off; off >>= 1) ss += __shfl_down(ss, off);
  ss = __shfl(ss, 0);
  float inv = 1.0f / fmaxf(sqrtf(ss), 1e-12f);
  row[lane] = make_float2(v.x*inv, v.y*inv);
}

// ---------------------------------------------------------------------------
extern "C" void kernel_launch(void* const* d_in, const int* in_sizes, int n_in,
                              void* d_out, int out_size, void* d_ws, size_t ws_size,
                              hipStream_t stream)
{
  const float* x     = (const float*)d_in[0];
  const int*   ei    = (const int*)d_in[1];
  const int*   etype = (const int*)d_in[2];
  const float* s1Wl  = (const float*)d_in[3];
  const float* s1Wr  = (const float*)d_in[4];
  const float* s1b   = (const float*)d_in[5];
  const float* s2Wl  = (const float*)d_in[6];
  const float* s2Wr  = (const float*)d_in[7];
  const float* s2b   = (const float*)d_in[8];
  const float* gatW  = (const float*)d_in[9];
  const float* att_s = (const float*)d_in[10];
  const float* att_d = (const float*)d_in[11];
  const float* gatb  = (const float*)d_in[12];
  const float* Wrel  = (const float*)d_in[13];
  const float* Wroot = (const float*)d_in[14];
  const float* rgcnb = (const float*)d_in[15];
  const float* fW    = (const float*)d_in[16];
  const float* fb    = (const float*)d_in[17];
  float* out = (float*)d_out;

  const int* src = ei;
  const int* dst = ei + NE;

  char* ws = (char*)d_ws;
  size_t off = 0;
  auto alloc = [&](size_t bytes) -> void* {
    void* p = ws + off;
    off = (off + bytes + 255) & ~(size_t)255;
    return p;
  };
  int*      deg    = (int*)alloc((size_t)NN * 4);
  int*      cntrel = (int*)alloc((size_t)NN * NREL * 4);
  int*      rowptr = (int*)alloc((size_t)(NN + 1) * 4);
  int*      cursor = (int*)alloc((size_t)NN * 4);
  int*      bsum   = (int*)alloc((size_t)NB * 4);
  int*      boff   = (int*)alloc((size_t)NB * 4);
  int*      srcs   = (int*)alloc((size_t)NE * 4);
  int*      ets    = (int*)alloc((size_t)NE * 4);
  int*      perm   = (int*)alloc((size_t)NE * 4);
  float*    al_s   = (float*)alloc((size_t)NN * 2 * 4);
  float*    al_d   = (float*)alloc((size_t)NN * 2 * 4);
  unsigned* mkey   = (unsigned*)alloc((size_t)NN * 2 * 4);
  float*    den    = (float*)alloc((size_t)NN * 2 * 4);
  float*    ex     = (float*)alloc((size_t)NE2 * 2 * 4);
  float*    S1     = (float*)alloc((size_t)NN * 512 * 4);  // means / h / xt
  float*    P1     = (float*)alloc((size_t)NN * 256 * 4);  // x_sage
  float*    P2     = (float*)alloc((size_t)NN * 256 * 4);  // x1, then x_gat
  float*    P3     = (float*)alloc((size_t)NN * 128 * 4);  // x_rgcn
  (void)ws_size; (void)in_sizes; (void)n_in; (void)out_size;

  const int NODEB = (NN + 3) / 4;   // 4 nodes (waves) per block

  // ---- counts + CSR build
  hipMemsetAsync(deg, 0, (size_t)NN * 4, stream);
  hipMemsetAsync(cntrel, 0, (size_t)NN * NREL * 4, stream);
  hipMemsetAsync(cursor, 0, (size_t)NN * 4, stream);
  k_counts<<<(NE + 255) / 256, 256, 0, stream>>>(src, dst, etype, deg, cntrel);
  k_scan1<<<NB, 256, 0, stream>>>(deg, bsum);
  k_scan2<<<1, 64, 0, stream>>>(bsum, boff, rowptr);
  k_scan3<<<NB, 256, 0, stream>>>(deg, boff, rowptr);
  k_fill<<<(NE + 255) / 256, 256, 0, stream>>>(src, dst, etype, rowptr, cursor, srcs, ets, perm);

  // ---- SAGE1: mean(x) -> S1 ; x1 = relu([mean|x]@[Wl;Wr]+b) -> P2
  k_csr_mean<7><<<NODEB, 256, 0, stream>>>(x, rowptr, srcs, S1);
  {
    dim3 g(256 / BN, (NN + BM - 1) / BM);
    k_gemm<<<g, 256, 0, stream>>>(S1, s1Wl, 128, x, s1Wr, 128, nullptr, nullptr, 0,
                                  s1b, P2, NN, 256, 1);
  }

  // ---- SAGE2: mean(x1) -> S1 ; x_sage -> P1
  k_csr_mean<8><<<NODEB, 256, 0, stream>>>(P2, rowptr, srcs, S1);
  {
    dim3 g(256 / BN, (NN + BM - 1) / BM);
    k_gemm<<<g, 256, 0, stream>>>(S1, s2Wl, 256, P2, s2Wr, 256, nullptr, nullptr, 0,
                                  s2b, P1, NN, 256, 1);
  }

  // ---- GAT: h = x_sage @ W -> S1 (N x 512)
  {
    dim3 g(512 / BN, (NN + BM - 1) / BM);
    k_gemm<<<g, 256, 0, stream>>>(P1, gatW, 256, nullptr, nullptr, 0, nullptr, nullptr, 0,
                                  nullptr, S1, NN, 512, 0);
  }
  k_gat_al<<<NN * 2, 64, 0, stream>>>(S1, att_s, att_d, al_s, al_d);
  hipMemsetAsync(mkey, 0, (size_t)NN * 2 * 4, stream);
  hipMemsetAsync(den, 0, (size_t)NN * 2 * 4, stream);
  k_gat_max<<<(NE2 + 255) / 256, 256, 0, stream>>>(src, dst, al_s, al_d, mkey);
  k_gat_exp<<<(NE2 + 255) / 256, 256, 0, stream>>>(src, dst, al_s, al_d, mkey, ex, den);
  k_gat_csr<<<NODEB, 256, 0, stream>>>(S1, rowptr, srcs, perm, ex, den, gatb, P2);

  // ---- RGCN: xt[r] = x_gat @ Wrel[r] -> S1 ; P3 = x_gat@Wroot + b ; add agg
  for (int r = 0; r < NREL; ++r) {
    dim3 g(128 / BN, (NN + BM - 1) / BM);
    k_gemm<<<g, 256, 0, stream>>>(P2, Wrel + (size_t)r * 256 * 128, 256,
                                  nullptr, nullptr, 0, nullptr, nullptr, 0,
                                  nullptr, S1 + (size_t)r * NN * 128, NN, 128, 0);
  }
  {
    dim3 g(128 / BN, (NN + BM - 1) / BM);
    k_gemm<<<g, 256, 0, stream>>>(P2, Wroot, 256, nullptr, nullptr, 0, nullptr, nullptr, 0,
                                  rgcnb, P3, NN, 128, 0);
  }
  k_rgcn_csr<<<NODEB, 256, 0, stream>>>(S1, rowptr, srcs, ets, cntrel, P3);

  // ---- fusion + L2 normalize
  {
    dim3 g(128 / BN, (NN + BM - 1) / BM);
    k_gemm<<<g, 256, 0, stream>>>(P1, fW, 256,
                                  P2, fW + 256 * 128, 256,
                                  P3, fW + 512 * 128, 128,
                                  fb, out, NN, 128, 0);
  }
  k_norm<<<(NN + 3) / 4, 256, 0, stream>>>(out);
}

// Round 3
// 1634.024 us; speedup vs baseline: 2.0343x; 1.1099x over previous
//
#include <hip/hip_runtime.h>
#include <math.h>

constexpr int NN   = 50000;
constexpr int NE   = 800000;
constexpr int NE2  = NE + NN;     // GAT adds self-loops
constexpr int NREL = 4;
constexpr int NB   = (NN + 255) / 256;   // scan blocks = 196

typedef __attribute__((ext_vector_type(8))) short bfrag;     // 8 bf16 (4 VGPRs)
typedef __attribute__((ext_vector_type(4))) float floatx4;   // MFMA acc

// ---------------------------------------------------------------------------
// counts: deg[dst], cntrel[dst*4+etype]
__global__ void k_counts(const int* __restrict__ src, const int* __restrict__ dst,
                         const int* __restrict__ et, int* deg, int* cntrel) {
  int e = blockIdx.x * blockDim.x + threadIdx.x;
  if (e < NE) {
    int d = dst[e];
    atomicAdd(&deg[d], 1);
    atomicAdd(&cntrel[d * NREL + et[e]], 1);
  }
}

// exclusive scan of deg -> rowptr
__global__ void k_scan1(const int* __restrict__ deg, int* bsum) {
  __shared__ int sm[256];
  int i = blockIdx.x * 256 + threadIdx.x;
  sm[threadIdx.x] = (i < NN) ? deg[i] : 0;
  __syncthreads();
  for (int s = 128; s; s >>= 1) {
    if (threadIdx.x < s) sm[threadIdx.x] += sm[threadIdx.x + s];
    __syncthreads();
  }
  if (threadIdx.x == 0) bsum[blockIdx.x] = sm[0];
}
__global__ void k_scan2(const int* __restrict__ bsum, int* boff, int* rowptr) {
  if (threadIdx.x == 0 && blockIdx.x == 0) {
    int acc = 0;
    for (int b = 0; b < NB; ++b) { boff[b] = acc; acc += bsum[b]; }
    rowptr[NN] = NE;
  }
}
__global__ void k_scan3(const int* __restrict__ deg, const int* __restrict__ boff,
                        int* rowptr) {
  __shared__ int sm[256];
  int i = blockIdx.x * 256 + threadIdx.x;
  int v = (i < NN) ? deg[i] : 0;
  sm[threadIdx.x] = v;
  __syncthreads();
  for (int s = 1; s < 256; s <<= 1) {
    int t = (threadIdx.x >= s) ? sm[threadIdx.x - s] : 0;
    __syncthreads();
    sm[threadIdx.x] += t;
    __syncthreads();
  }
  if (i < NN) rowptr[i] = boff[blockIdx.x] + sm[threadIdx.x] - v;  // exclusive
}

__global__ void k_fill(const int* __restrict__ src, const int* __restrict__ dst,
                       const int* __restrict__ et, const int* __restrict__ rowptr,
                       int* cursor, int* srcs, int* ets, int* perm) {
  int e = blockIdx.x * blockDim.x + threadIdx.x;
  if (e >= NE) return;
  int d = dst[e];
  int pos = rowptr[d] + atomicAdd(&cursor[d], 1);
  srcs[pos] = src[e];
  ets[pos]  = et[e];
  perm[pos] = e;
}

// ---------------------------------------------------------------------------
// CSR mean aggregation: one wave per dst node
template<int CSH>
__global__ void k_csr_mean(const float* __restrict__ xin, const int* __restrict__ rowptr,
                           const int* __restrict__ srcs, float* __restrict__ outp) {
  int node = blockIdx.x * 4 + (threadIdx.x >> 6);
  int lane = threadIdx.x & 63;
  if (node >= NN) return;
  int p0 = rowptr[node], p1 = rowptr[node + 1];
  constexpr int R = (1 << CSH) / 64;
  float acc[R] = {};
  int p = p0;
  int s = (p < p1) ? srcs[p] : 0;
  while (p < p1) {
    int sn = (p + 1 < p1) ? srcs[p + 1] : 0;
    const float* row = xin + ((size_t)s << CSH);
#pragma unroll
    for (int j = 0; j < R; ++j) acc[j] += row[lane + 64 * j];
    s = sn; ++p;
  }
  float inv = (p1 > p0) ? 1.0f / (float)(p1 - p0) : 0.0f;
  float* orow = outp + ((size_t)node << CSH);
#pragma unroll
  for (int j = 0; j < R; ++j) orow[lane + 64 * j] = acc[j] * inv;
}

// ---------------------------------------------------------------------------
// split-bf16 MFMA GEMM: fp32 emulated as hi/lo bf16, 3 MFMAs per tile pair.
// C = scale*([A0|A1|A2] @ [B0;B1;B2]) + bias (+relu). K_i%32==0, Nc%128==0.
// A_i: M x K_i (row stride lda_i), B_i: K_i x Nc (row stride ldb_i).
// blockIdx.z batches pair0's B and the output (zsB/zsC element strides).
__device__ inline void split2(float x, unsigned short& h, unsigned short& l) {
  unsigned u = __float_as_uint(x);
  h = (unsigned short)(u >> 16);                     // truncated hi
  float hif = __uint_as_float(u & 0xFFFF0000u);
  float lo  = x - hif;                               // exact residual
  l = (unsigned short)(__float_as_uint(lo) >> 16);
}

__global__ __launch_bounds__(256)
void k_gemm_mfma(const float* A0, int lda0, const float* B0, int ldb0, int K0,
                 const float* A1, int lda1, const float* B1, int ldb1, int K1,
                 const float* A2, int lda2, const float* B2, int ldb2, int K2,
                 const float* __restrict__ bias, float* Cout, int M, int Nc,
                 float scale, int do_relu, long zsB, long zsC)
{
  // fragment-major LDS: [8 tiles][64 lanes][8 bf16]
  __shared__ short Ah[8*64*8], Al[8*64*8], Bh[8*64*8], Bl[8*64*8];
  const int tid  = threadIdx.x;
  const int lane = tid & 63;
  const int wv   = tid >> 6;          // 0..3
  const int wm   = wv >> 1, wn = wv & 1;
  const int row0 = blockIdx.y * 128;
  const int col0 = blockIdx.x * 128;
  if (zsB) { B0 += (long)blockIdx.z * zsB; Cout += (long)blockIdx.z * zsC; }

  floatx4 acc[4][4];
#pragma unroll
  for (int i = 0; i < 4; ++i)
#pragma unroll
    for (int j = 0; j < 4; ++j) acc[i][j] = 0;

  const int a_m   = tid >> 1;          // 0..127
  const int a_kq0 = (tid & 1) * 2;     // k-quads {a_kq0, a_kq0+1}
  const int b_n   = tid & 127;         // 0..127
  const int b_q0  = tid >> 7;          // k-quads {b_q0, b_q0+2}

  const float* Aarr[3] = {A0, A1, A2};
  const float* Barr[3] = {B0, B1, B2};
  const int ldaArr[3] = {lda0, lda1, lda2};
  const int ldbArr[3] = {ldb0, ldb1, ldb2};
  const int Karr[3]   = {K0, K1, K2};

  for (int p = 0; p < 3; ++p) {
    const int K = Karr[p];
    if (K == 0) continue;
    const int lda = ldaArr[p], ldb = ldbArr[p];
    const bool arow_ok = (row0 + a_m) < M;
    const float* Arow = Aarr[p] + (size_t)(row0 + a_m) * lda;
    const float* Bbase = Barr[p] + col0 + b_n;

    for (int kt = 0; kt < K; kt += 32) {
      // ---- load + split-convert A (16 floats: 2 k-quads of 8)
      bfrag avh[2], avl[2];
#pragma unroll
      for (int c = 0; c < 2; ++c) {
        const float* ap = Arow + kt + (a_kq0 + c) * 8;
#pragma unroll
        for (int i = 0; i < 8; ++i) {
          float x = arow_ok ? ap[i] : 0.0f;
          unsigned short h, l; split2(x, h, l);
          avh[c][i] = (short)h; avl[c][i] = (short)l;
        }
      }
      // ---- load + split-convert B (2 k-quads of 8, column b_n)
      bfrag bvh[2], bvl[2];
#pragma unroll
      for (int c = 0; c < 2; ++c) {
        const float* bp = Bbase + (size_t)(kt + (b_q0 + c*2) * 8) * ldb;
#pragma unroll
        for (int j = 0; j < 8; ++j) {
          float x = bp[(size_t)j * ldb];
          unsigned short h, l; split2(x, h, l);
          bvh[c][j] = (short)h; bvl[c][j] = (short)l;
        }
      }
      __syncthreads();   // previous tile's reads done
#pragma unroll
      for (int c = 0; c < 2; ++c) {
        int q = a_kq0 + c;
        int idx = ((a_m >> 4) * 64 + ((a_m & 15) | (q << 4))) * 8;
        *(bfrag*)&Ah[idx] = avh[c];
        *(bfrag*)&Al[idx] = avl[c];
      }
#pragma unroll
      for (int c = 0; c < 2; ++c) {
        int q = b_q0 + c*2;
        int idx = ((b_n >> 4) * 64 + ((b_n & 15) | (q << 4))) * 8;
        *(bfrag*)&Bh[idx] = bvh[c];
        *(bfrag*)&Bl[idx] = bvl[c];
      }
      __syncthreads();

      bfrag afh[4], afl[4], bfh[4], bfl[4];
#pragma unroll
      for (int mt = 0; mt < 4; ++mt) {
        int idx = ((wm*4 + mt) * 64 + lane) * 8;
        afh[mt] = *(bfrag*)&Ah[idx];
        afl[mt] = *(bfrag*)&Al[idx];
      }
#pragma unroll
      for (int nt = 0; nt < 4; ++nt) {
        int idx = ((wn*4 + nt) * 64 + lane) * 8;
        bfh[nt] = *(bfrag*)&Bh[idx];
        bfl[nt] = *(bfrag*)&Bl[idx];
      }
#pragma unroll
      for (int mt = 0; mt < 4; ++mt)
#pragma unroll
        for (int nt = 0; nt < 4; ++nt) {
          acc[mt][nt] = __builtin_amdgcn_mfma_f32_16x16x32_bf16(afh[mt], bfh[nt], acc[mt][nt], 0, 0, 0);
          acc[mt][nt] = __builtin_amdgcn_mfma_f32_16x16x32_bf16(afh[mt], bfl[nt], acc[mt][nt], 0, 0, 0);
          acc[mt][nt] = __builtin_amdgcn_mfma_f32_16x16x32_bf16(afl[mt], bfh[nt], acc[mt][nt], 0, 0, 0);
        }
    }
  }

  // epilogue: C/D layout col=lane&15, row=(lane>>4)*4+reg   [m89-verified]
  const int cl = lane & 15;
  const int rq = lane >> 4;
#pragma unroll
  for (int mt = 0; mt < 4; ++mt)
#pragma unroll
    for (int r = 0; r < 4; ++r) {
      int row = row0 + wm*64 + mt*16 + rq*4 + r;
      if (row < M) {
#pragma unroll
        for (int nt = 0; nt < 4; ++nt) {
          int colx = col0 + wn*64 + nt*16 + cl;
          float v = acc[mt][nt][r] * scale + (bias ? bias[colx] : 0.0f);
          if (do_relu) v = fmaxf(v, 0.0f);
          Cout[(size_t)row * Nc + colx] = v;
        }
      }
    }
}

// ---------------------------------------------------------------------------
// GAT pieces (restructured: never materialize h)
__device__ inline unsigned f2key(float f) {
  unsigned b = __float_as_uint(f);
  return (b & 0x80000000u) ? ~b : (b | 0x80000000u);
}
__device__ inline float key2f(unsigned k) {
  unsigned b = (k & 0x80000000u) ? (k & 0x7FFFFFFFu) : ~k;
  return __uint_as_float(b);
}

// wt[4][256] = {W@att_s(h0), W@att_s(h1), W@att_d(h0), W@att_d(h1)}
__global__ void k_wtilde(const float* __restrict__ gatW, const float* __restrict__ att_s,
                         const float* __restrict__ att_d, float* __restrict__ wt) {
  int k = threadIdx.x;               // 256 threads
  const float* Wr = gatW + (size_t)k * 512;
  float s0 = 0, s1 = 0, d0 = 0, d1 = 0;
  for (int i = 0; i < 256; ++i) {
    float w0 = Wr[i], w1 = Wr[256 + i];
    s0 += w0 * att_s[i];       s1 += w1 * att_s[256 + i];
    d0 += w0 * att_d[i];       d1 += w1 * att_d[256 + i];
  }
  wt[k] = s0; wt[256 + k] = s1; wt[512 + k] = d0; wt[768 + k] = d1;
}

// per-node logits: al[n,h] = x_sage[n] . wt[h]
__global__ void k_al(const float* __restrict__ P1, const float* __restrict__ wt,
                     float* __restrict__ al_s, float* __restrict__ al_d) {
  int node = blockIdx.x * 4 + (threadIdx.x >> 6);
  int lane = threadIdx.x & 63;
  if (node >= NN) return;
  float4 v = ((const float4*)(P1 + (size_t)node * 256))[lane];
  const float4* w = (const float4*)wt;
  float4 a0 = w[lane], a1 = w[64 + lane], a2 = w[128 + lane], a3 = w[192 + lane];
  float s0 = v.x*a0.x + v.y*a0.y + v.z*a0.z + v.w*a0.w;
  float s1 = v.x*a1.x + v.y*a1.y + v.z*a1.z + v.w*a1.w;
  float s2 = v.x*a2.x + v.y*a2.y + v.z*a2.z + v.w*a2.w;
  float s3 = v.x*a3.x + v.y*a3.y + v.z*a3.z + v.w*a3.w;
  for (int off = 32; off; off >>= 1) {
    s0 += __shfl_down(s0, off); s1 += __shfl_down(s1, off);
    s2 += __shfl_down(s2, off); s3 += __shfl_down(s3, off);
  }
  if (lane == 0) {
    al_s[node*2] = s0; al_s[node*2 + 1] = s1;
    al_d[node*2] = s2; al_d[node*2 + 1] = s3;
  }
}

__global__ void k_gat_max(const int* __restrict__ src, const int* __restrict__ dst,
                          const float* __restrict__ al_s, const float* __restrict__ al_d,
                          unsigned* mkey) {
  int e = blockIdx.x * blockDim.x + threadIdx.x;
  if (e >= NE2) return;
  int s, d;
  if (e < NE) { s = src[e]; d = dst[e]; } else { s = d = e - NE; }
#pragma unroll
  for (int hd = 0; hd < 2; ++hd) {
    float v = al_s[s*2 + hd] + al_d[d*2 + hd];
    v = v > 0.f ? v : 0.2f * v;
    atomicMax(&mkey[d*2 + hd], f2key(v));
  }
}

__global__ void k_gat_exp(const int* __restrict__ src, const int* __restrict__ dst,
                          const float* __restrict__ al_s, const float* __restrict__ al_d,
                          const unsigned* __restrict__ mkey, float* ex, float* den) {
  int e = blockIdx.x * blockDim.x + threadIdx.x;
  if (e >= NE2) return;
  int s, d;
  if (e < NE) { s = src[e]; d = dst[e]; } else { s = d = e - NE; }
#pragma unroll
  for (int hd = 0; hd < 2; ++hd) {
    float v = al_s[s*2 + hd] + al_d[d*2 + hd];
    v = v > 0.f ? v : 0.2f * v;
    float m = key2f(mkey[d*2 + hd]);
    float xv = __expf(v - m);
    ex[(size_t)e*2 + hd] = xv;
    atomicAdd(&den[d*2 + hd], xv);
  }
}

// CSR GAT aggregation over x_sage (256 ch): AGG[node] = [sum a0*xs | sum a1*xs]
__global__ void k_gat_csr(const float* __restrict__ xs, const int* __restrict__ rowptr,
                          const int* __restrict__ srcs, const int* __restrict__ perm,
                          const float* __restrict__ ex, const float* __restrict__ den,
                          float* __restrict__ AGG) {
  int node = blockIdx.x * 4 + (threadIdx.x >> 6);
  int lane = threadIdx.x & 63;
  if (node >= NN) return;
  int p0 = rowptr[node], p1 = rowptr[node + 1];
  float d0 = 1.0f / fmaxf(den[node*2 + 0], 1e-16f);
  float d1 = 1.0f / fmaxf(den[node*2 + 1], 1e-16f);
  float acc0[4], acc1[4];
  {  // self loop
    float a0 = ex[(size_t)(NE + node)*2]     * d0;
    float a1 = ex[(size_t)(NE + node)*2 + 1] * d1;
    const float* row = xs + ((size_t)node << 8);
#pragma unroll
    for (int j = 0; j < 4; ++j) {
      float v = row[lane + 64*j];
      acc0[j] = a0 * v; acc1[j] = a1 * v;
    }
  }
  int p = p0;
  int s = 0, e = 0;
  if (p < p1) { s = srcs[p]; e = perm[p]; }
  while (p < p1) {
    int sn = 0, en = 0;
    if (p + 1 < p1) { sn = srcs[p+1]; en = perm[p+1]; }
    float a0 = ex[(size_t)e*2]     * d0;
    float a1 = ex[(size_t)e*2 + 1] * d1;
    const float* row = xs + ((size_t)s << 8);
#pragma unroll
    for (int j = 0; j < 4; ++j) {
      float v = row[lane + 64*j];
      acc0[j] += a0 * v; acc1[j] += a1 * v;
    }
    s = sn; e = en; ++p;
  }
  float* orow = AGG + ((size_t)node << 9);
#pragma unroll
  for (int j = 0; j < 4; ++j) {
    orow[lane + 64*j]       = acc0[j];
    orow[256 + lane + 64*j] = acc1[j];
  }
}

// ---------------------------------------------------------------------------
// CSR RGCN aggregation: adds into P3 (= x_gat@Wroot + b, precomputed)
__global__ void k_rgcn_csr(const float* __restrict__ xt, const int* __restrict__ rowptr,
                           const int* __restrict__ srcs, const int* __restrict__ ets,
                           const int* __restrict__ cntrel, float* __restrict__ outp) {
  int node = blockIdx.x * 4 + (threadIdx.x >> 6);
  int lane = threadIdx.x & 63;
  if (node >= NN) return;
  int p0 = rowptr[node], p1 = rowptr[node + 1];
  float inv[NREL];
#pragma unroll
  for (int r = 0; r < NREL; ++r) {
    int c = cntrel[node*NREL + r];
    inv[r] = c ? 1.0f / (float)c : 0.0f;
  }
  float acc0 = 0.f, acc1 = 0.f;
  int p = p0;
  int s = 0, r = 0;
  if (p < p1) { s = srcs[p]; r = ets[p]; }
  while (p < p1) {
    int sn = 0, rn = 0;
    if (p + 1 < p1) { sn = srcs[p+1]; rn = ets[p+1]; }
    const float* row = xt + (((size_t)r * NN + s) << 7);
    float w = inv[r];
    acc0 += row[lane] * w;
    acc1 += row[lane + 64] * w;
    s = sn; r = rn; ++p;
  }
  float* orow = outp + ((size_t)node << 7);
  orow[lane]      += acc0;
  orow[lane + 64] += acc1;
}

// ---------------------------------------------------------------------------
__global__ void k_norm(float* __restrict__ out) {
  int gw = (int)(((long)blockIdx.x * blockDim.x + threadIdx.x) >> 6);
  int lane = threadIdx.x & 63;
  if (gw >= NN) return;
  float2* row = (float2*)(out + (size_t)gw * 128);
  float2 v = row[lane];
  float ss = v.x*v.x + v.y*v.y;
  for (int off = 32; off; off >>= 1) ss += __shfl_down(ss, off);
  ss = __shfl(ss, 0);
  float inv = 1.0f / fmaxf(sqrtf(ss), 1e-12f);
  row[lane] = make_float2(v.x*inv, v.y*inv);
}

// ---------------------------------------------------------------------------
extern "C" void kernel_launch(void* const* d_in, const int* in_sizes, int n_in,
                              void* d_out, int out_size, void* d_ws, size_t ws_size,
                              hipStream_t stream)
{
  const float* x     = (const float*)d_in[0];
  const int*   ei    = (const int*)d_in[1];
  const int*   etype = (const int*)d_in[2];
  const float* s1Wl  = (const float*)d_in[3];
  const float* s1Wr  = (const float*)d_in[4];
  const float* s1b   = (const float*)d_in[5];
  const float* s2Wl  = (const float*)d_in[6];
  const float* s2Wr  = (const float*)d_in[7];
  const float* s2b   = (const float*)d_in[8];
  const float* gatW  = (const float*)d_in[9];
  const float* att_s = (const float*)d_in[10];
  const float* att_d = (const float*)d_in[11];
  const float* gatb  = (const float*)d_in[12];
  const float* Wrel  = (const float*)d_in[13];
  const float* Wroot = (const float*)d_in[14];
  const float* rgcnb = (const float*)d_in[15];
  const float* fW    = (const float*)d_in[16];
  const float* fb    = (const float*)d_in[17];
  float* out = (float*)d_out;

  const int* src = ei;
  const int* dst = ei + NE;

  char* ws = (char*)d_ws;
  size_t off = 0;
  auto alloc = [&](size_t bytes) -> void* {
    void* p = ws + off;
    off = (off + bytes + 255) & ~(size_t)255;
    return p;
  };
  int*      deg    = (int*)alloc((size_t)NN * 4);
  int*      cntrel = (int*)alloc((size_t)NN * NREL * 4);
  int*      rowptr = (int*)alloc((size_t)(NN + 1) * 4);
  int*      cursor = (int*)alloc((size_t)NN * 4);
  int*      bsum   = (int*)alloc((size_t)NB * 4);
  int*      boff   = (int*)alloc((size_t)NB * 4);
  int*      srcs   = (int*)alloc((size_t)NE * 4);
  int*      ets    = (int*)alloc((size_t)NE * 4);
  int*      perm   = (int*)alloc((size_t)NE * 4);
  float*    al_s   = (float*)alloc((size_t)NN * 2 * 4);
  float*    al_d   = (float*)alloc((size_t)NN * 2 * 4);
  unsigned* mkey   = (unsigned*)alloc((size_t)NN * 2 * 4);
  float*    den    = (float*)alloc((size_t)NN * 2 * 4);
  float*    ex     = (float*)alloc((size_t)NE2 * 2 * 4);
  float*    wt     = (float*)alloc((size_t)4 * 256 * 4);
  float*    S1     = (float*)alloc((size_t)NN * 512 * 4);  // means / AGG / xt
  float*    P1     = (float*)alloc((size_t)NN * 256 * 4);  // x_sage
  float*    P2     = (float*)alloc((size_t)NN * 256 * 4);  // x1, then x_gat
  float*    P3     = (float*)alloc((size_t)NN * 128 * 4);  // x_rgcn
  (void)ws_size; (void)in_sizes; (void)n_in; (void)out_size;

  const int NODEB = (NN + 3) / 4;     // 4 waves (nodes) per block
  const int GY = (NN + 127) / 128;    // GEMM row blocks = 391

  // ---- counts + CSR build
  hipMemsetAsync(deg, 0, (size_t)NN * 4, stream);
  hipMemsetAsync(cntrel, 0, (size_t)NN * NREL * 4, stream);
  hipMemsetAsync(cursor, 0, (size_t)NN * 4, stream);
  k_counts<<<(NE + 255) / 256, 256, 0, stream>>>(src, dst, etype, deg, cntrel);
  k_scan1<<<NB, 256, 0, stream>>>(deg, bsum);
  k_scan2<<<1, 64, 0, stream>>>(bsum, boff, rowptr);
  k_scan3<<<NB, 256, 0, stream>>>(deg, boff, rowptr);
  k_fill<<<(NE + 255) / 256, 256, 0, stream>>>(src, dst, etype, rowptr, cursor, srcs, ets, perm);

  // ---- SAGE1: mean(x) -> S1 ; x1 = relu([mean|x]@[Wl;Wr]+b) -> P2
  k_csr_mean<7><<<NODEB, 256, 0, stream>>>(x, rowptr, srcs, S1);
  k_gemm_mfma<<<dim3(2, GY, 1), 256, 0, stream>>>(
      S1, 128, s1Wl, 256, 128,  x, 128, s1Wr, 256, 128,  nullptr, 0, nullptr, 0, 0,
      s1b, P2, NN, 256, 1.0f, 1, 0, 0);

  // ---- SAGE2: mean(x1) -> S1 ; x_sage = relu([mean|x1]@[Wl;Wr]+b) -> P1
  k_csr_mean<8><<<NODEB, 256, 0, stream>>>(P2, rowptr, srcs, S1);
  k_gemm_mfma<<<dim3(2, GY, 1), 256, 0, stream>>>(
      S1, 256, s2Wl, 256, 256,  P2, 256, s2Wr, 256, 256,  nullptr, 0, nullptr, 0, 0,
      s2b, P1, NN, 256, 1.0f, 1, 0, 0);

  // ---- GAT (h never materialized)
  k_wtilde<<<1, 256, 0, stream>>>(gatW, att_s, att_d, wt);
  k_al<<<NODEB, 256, 0, stream>>>(P1, wt, al_s, al_d);
  hipMemsetAsync(mkey, 0, (size_t)NN * 2 * 4, stream);
  hipMemsetAsync(den, 0, (size_t)NN * 2 * 4, stream);
  k_gat_max<<<(NE2 + 255) / 256, 256, 0, stream>>>(src, dst, al_s, al_d, mkey);
  k_gat_exp<<<(NE2 + 255) / 256, 256, 0, stream>>>(src, dst, al_s, al_d, mkey, ex, den);
  k_gat_csr<<<NODEB, 256, 0, stream>>>(P1, rowptr, srcs, perm, ex, den, S1);
  // x_gat = relu(0.5*(agg0@W0 + agg1@W1) + b) -> P2
  k_gemm_mfma<<<dim3(2, GY, 1), 256, 0, stream>>>(
      S1, 512, gatW, 512, 256,  S1 + 256, 512, gatW + 256, 512, 256,
      nullptr, 0, nullptr, 0, 0,
      gatb, P2, NN, 256, 0.5f, 1, 0, 0);

  // ---- RGCN: xt[r] = x_gat @ Wrel[r] -> S1 (batched over z); root -> P3; agg
  k_gemm_mfma<<<dim3(1, GY, NREL), 256, 0, stream>>>(
      P2, 256, Wrel, 128, 256,  nullptr, 0, nullptr, 0, 0,  nullptr, 0, nullptr, 0, 0,
      nullptr, S1, NN, 128, 1.0f, 0, (long)256 * 128, (long)NN * 128);
  k_gemm_mfma<<<dim3(1, GY, 1), 256, 0, stream>>>(
      P2, 256, Wroot, 128, 256,  nullptr, 0, nullptr, 0, 0,  nullptr, 0, nullptr, 0, 0,
      rgcnb, P3, NN, 128, 1.0f, 0, 0, 0);
  k_rgcn_csr<<<NODEB, 256, 0, stream>>>(S1, rowptr, srcs, ets, cntrel, P3);

  // ---- fusion + L2 normalize
  k_gemm_mfma<<<dim3(1, GY, 1), 256, 0, stream>>>(
      P1, 256, fW, 128, 256,  P2, 256, fW + 256*128, 128, 256,  P3, 128, fW + 512*128, 128, 128,
      fb, out, NN, 128, 1.0f, 0, 0, 0);
  k_norm<<<(NN + 3) / 4, 256, 0, stream>>>(out);
}

// Round 5
// 1271.286 us; speedup vs baseline: 2.6147x; 1.2853x over previous
//
#include <hip/hip_runtime.h>
#include <math.h>

constexpr int NN   = 50000;
constexpr int NE   = 800000;
constexpr int NREL = 4;
constexpr int NB   = (NN + 255) / 256;   // scan blocks

typedef __attribute__((ext_vector_type(8))) short bfrag;     // 8 bf16 (4 VGPRs)
typedef __attribute__((ext_vector_type(4))) float floatx4;   // MFMA acc

__device__ inline void split2(float x, unsigned short& h, unsigned short& l) {
  unsigned u = __float_as_uint(x);
  h = (unsigned short)(u >> 16);                     // truncated hi
  float hif = __uint_as_float(u & 0xFFFF0000u);
  float lo  = x - hif;                               // exact residual
  l = (unsigned short)(__float_as_uint(lo) >> 16);
}
__device__ inline float join2(unsigned short h, unsigned short l) {
  return __uint_as_float((unsigned)h << 16) + __uint_as_float((unsigned)l << 16);
}

// ---------------------------------------------------------------------------
__global__ void k_counts(const int* __restrict__ src, const int* __restrict__ dst,
                         const int* __restrict__ et, int* deg, int* cntrel) {
  int e = blockIdx.x * blockDim.x + threadIdx.x;
  if (e < NE) {
    int d = dst[e];
    atomicAdd(&deg[d], 1);
    atomicAdd(&cntrel[d * NREL + et[e]], 1);
  }
}

__global__ void k_scan1(const int* __restrict__ deg, int* bsum) {
  __shared__ int sm[256];
  int i = blockIdx.x * 256 + threadIdx.x;
  sm[threadIdx.x] = (i < NN) ? deg[i] : 0;
  __syncthreads();
  for (int s = 128; s; s >>= 1) {
    if (threadIdx.x < s) sm[threadIdx.x] += sm[threadIdx.x + s];
    __syncthreads();
  }
  if (threadIdx.x == 0) bsum[blockIdx.x] = sm[0];
}
__global__ void k_scan2(const int* __restrict__ bsum, int* boff, int* rowptr) {
  if (threadIdx.x == 0 && blockIdx.x == 0) {
    int acc = 0;
    for (int b = 0; b < NB; ++b) { boff[b] = acc; acc += bsum[b]; }
    rowptr[NN] = NE;
  }
}
__global__ void k_scan3(const int* __restrict__ deg, const int* __restrict__ boff,
                        int* rowptr) {
  __shared__ int sm[256];
  int i = blockIdx.x * 256 + threadIdx.x;
  int v = (i < NN) ? deg[i] : 0;
  sm[threadIdx.x] = v;
  __syncthreads();
  for (int s = 1; s < 256; s <<= 1) {
    int t = (threadIdx.x >= s) ? sm[threadIdx.x - s] : 0;
    __syncthreads();
    sm[threadIdx.x] += t;
    __syncthreads();
  }
  if (i < NN) rowptr[i] = boff[blockIdx.x] + sm[threadIdx.x] - v;  // exclusive
}

__global__ void k_fill(const int* __restrict__ src, const int* __restrict__ dst,
                       const int* __restrict__ et, const int* __restrict__ rowptr,
                       int* cursor, int* srcs, int* ets) {
  int e = blockIdx.x * blockDim.x + threadIdx.x;
  if (e >= NE) return;
  int d = dst[e];
  int pos = rowptr[d] + atomicAdd(&cursor[d], 1);
  srcs[pos] = src[e];
  ets[pos]  = et[e];
}

// ---------------------------------------------------------------------------
// weight packing into MFMA fragment order (hi/lo planes), done once per launch.
#define PK_N 14
__device__ __constant__ const int PK_BASE[PK_N]  = {0,1,2,3,4,4,5,5,5,5,6,7,7,7};
__device__ __constant__ const int PK_EOFF[PK_N]  = {0,0,0,0,0,256,0,32768,65536,98304,0,0,32768,65536};
__device__ __constant__ const int PK_K[PK_N]     = {128,128,256,256,256,256,256,256,256,256,256,256,256,128};
__device__ __constant__ const int PK_LDB[PK_N]   = {256,256,256,256,512,512,128,128,128,128,128,128,128,128};
__device__ __constant__ const int PK_START[PK_N] = {0,4096,8192,16384,24576,32768,40960,45056,49152,53248,57344,61440,65536,69632};
constexpr int PK_TOTAL = 71680;
constexpr int BF_S1WL = 0,     BF_S1WR = 4096,  BF_S2WL = 8192,  BF_S2WR = 16384;
constexpr int BF_GATW0 = 24576, BF_GATW1 = 32768, BF_WREL = 40960, BF_WROOT = 57344;
constexpr int BF_FW0 = 61440,  BF_FW1 = 65536,  BF_FW2 = 69632;

__global__ void k_pack(const float* b0, const float* b1, const float* b2, const float* b3,
                       const float* b4, const float* b5, const float* b6, const float* b7,
                       unsigned short* __restrict__ Bh, unsigned short* __restrict__ Bl) {
  int f = blockIdx.x * 256 + threadIdx.x;
  if (f >= PK_TOTAL) return;
  int m = 0;
#pragma unroll
  for (int i = 1; i < PK_N; ++i) if (f >= PK_START[i]) m = i;
  const float* bases[8] = {b0,b1,b2,b3,b4,b5,b6,b7};
  int lf = f - PK_START[m];
  int K = PK_K[m], ldb = PK_LDB[m];
  int Kq16 = K << 1;
  int ntile = lf / Kq16;
  int rem = lf - ntile * Kq16;
  int kq = rem >> 4, c = rem & 15;
  const float* sp = bases[PK_BASE[m]] + PK_EOFF[m] + (size_t)(kq * 8) * ldb + ntile * 16 + c;
#pragma unroll
  for (int j = 0; j < 8; ++j) {
    unsigned short h, l; split2(sp[(size_t)j * ldb], h, l);
    Bh[(size_t)f * 8 + j] = h;
    Bl[(size_t)f * 8 + j] = l;
  }
}

// x -> hi/lo planes
__global__ void k_split(const float* __restrict__ x, unsigned short* __restrict__ xh,
                        unsigned short* __restrict__ xl, long total4) {
  long i = (long)blockIdx.x * blockDim.x + threadIdx.x;
  if (i >= total4) return;
  float4 v = ((const float4*)x)[i];
  ushort4 h, l;
  split2(v.x, h.x, l.x); split2(v.y, h.y, l.y);
  split2(v.z, h.z, l.z); split2(v.w, h.w, l.w);
  ((ushort4*)xh)[i] = h;
  ((ushort4*)xl)[i] = l;
}

// ---------------------------------------------------------------------------
// CSR mean, 128 ch, reads fp32 input x, writes split planes
__global__ void k_mean128(const float* __restrict__ xin, const int* __restrict__ rowptr,
                          const int* __restrict__ srcs,
                          unsigned short* __restrict__ oh, unsigned short* __restrict__ ol) {
  int node = blockIdx.x * 4 + (threadIdx.x >> 6);
  int lane = threadIdx.x & 63;
  if (node >= NN) return;
  int p0 = rowptr[node], p1 = rowptr[node + 1];
  float2 acc = make_float2(0.f, 0.f);
  int p = p0;
  int s = (p < p1) ? srcs[p] : 0;
  while (p < p1) {
    int sn = (p + 1 < p1) ? srcs[p + 1] : 0;
    float2 v = ((const float2*)(xin + ((size_t)s << 7)))[lane];
    acc.x += v.x; acc.y += v.y;
    s = sn; ++p;
  }
  float inv = (p1 > p0) ? 1.0f / (float)(p1 - p0) : 0.0f;
  ushort2 h, l;
  split2(acc.x * inv, h.x, l.x); split2(acc.y * inv, h.y, l.y);
  size_t o = ((size_t)node << 7) + lane * 2;
  *(ushort2*)(oh + o) = h;
  *(ushort2*)(ol + o) = l;
}

// CSR mean, 256 ch, reads hi/lo planes, writes split planes
__global__ void k_mean256p(const unsigned short* __restrict__ ih, const unsigned short* __restrict__ il,
                           const int* __restrict__ rowptr, const int* __restrict__ srcs,
                           unsigned short* __restrict__ oh, unsigned short* __restrict__ ol) {
  int node = blockIdx.x * 4 + (threadIdx.x >> 6);
  int lane = threadIdx.x & 63;
  if (node >= NN) return;
  int p0 = rowptr[node], p1 = rowptr[node + 1];
  float4 acc = make_float4(0.f, 0.f, 0.f, 0.f);
  int p = p0;
  int s = (p < p1) ? srcs[p] : 0;
  while (p < p1) {
    int sn = (p + 1 < p1) ? srcs[p + 1] : 0;
    size_t o = ((size_t)s << 8) + lane * 4;
    ushort4 hv = *(const ushort4*)(ih + o);
    ushort4 lv = *(const ushort4*)(il + o);
    acc.x += join2(hv.x, lv.x); acc.y += join2(hv.y, lv.y);
    acc.z += join2(hv.z, lv.z); acc.w += join2(hv.w, lv.w);
    s = sn; ++p;
  }
  float inv = (p1 > p0) ? 1.0f / (float)(p1 - p0) : 0.0f;
  ushort4 h, l;
  split2(acc.x * inv, h.x, l.x); split2(acc.y * inv, h.y, l.y);
  split2(acc.z * inv, h.z, l.z); split2(acc.w * inv, h.w, l.w);
  size_t o = ((size_t)node << 8) + lane * 4;
  *(ushort4*)(oh + o) = h;
  *(ushort4*)(ol + o) = l;
}

// ---------------------------------------------------------------------------
// split-bf16 MFMA GEMM with pre-split A planes and fragment-packed B planes.
__global__ __launch_bounds__(256)
void k_gemm_mfma(const unsigned short* __restrict__ Bph, const unsigned short* __restrict__ Bpl,
                 const unsigned short* A0h, const unsigned short* A0l, int lda0, int bf0, int K0,
                 const unsigned short* A1h, const unsigned short* A1l, int lda1, int bf1, int K1,
                 const unsigned short* A2h, const unsigned short* A2l, int lda2, int bf2, int K2,
                 const float* __restrict__ bias, float* Cf,
                 unsigned short* Ch, unsigned short* Cl,
                 int M, int Nc, float scale, int do_relu, int zsB, long zsC)
{
  __shared__ short Ash[8*64*8], Asl[8*64*8], Bsh[8*64*8], Bsl[8*64*8];
  const int tid  = threadIdx.x;
  const int lane = tid & 63;
  const int wv   = tid >> 6;
  const int wm   = wv >> 1, wn = wv & 1;
  const int row0 = blockIdx.y * 128;
  const int col0 = blockIdx.x * 128;
  if (zsB) {
    bf0 += blockIdx.z * zsB;
    long zc = (long)blockIdx.z * zsC;
    if (Cf) Cf += zc;
    if (Ch) { Ch += zc; Cl += zc; }
  }

  floatx4 acc[4][4];
#pragma unroll
  for (int i = 0; i < 4; ++i)
#pragma unroll
    for (int j = 0; j < 4; ++j) acc[i][j] = 0;

  const int a_m = tid >> 1;
  const int a_h = tid & 1;
  const int b_nt = tid >> 5;
  const int b_rem = (tid << 1) & 63;

  const unsigned short* Aharr[3] = {A0h, A1h, A2h};
  const unsigned short* Alarr[3] = {A0l, A1l, A2l};
  const int ldaArr[3] = {lda0, lda1, lda2};
  const int bfArr[3]  = {bf0, bf1, bf2};
  const int Karr[3]   = {K0, K1, K2};

  for (int p = 0; p < 3; ++p) {
    const int K = Karr[p];
    if (K == 0) continue;
    const int lda = ldaArr[p];
    const bool arow_ok = (row0 + a_m) < M;
    const unsigned short* Arh = Aharr[p] + (size_t)(row0 + a_m) * lda + a_h * 16;
    const unsigned short* Arl = Alarr[p] + (size_t)(row0 + a_m) * lda + a_h * 16;
    const int Kq16 = K << 1;
    const int bbase = bfArr[p] + (col0 >> 4) * Kq16 + b_nt * Kq16 + b_rem;

    for (int kt = 0; kt < K; kt += 32) {
      bfrag ah0, ah1, al0, al1;
      if (arow_ok) {
        ah0 = *(const bfrag*)(Arh + kt);
        ah1 = *(const bfrag*)(Arh + kt + 8);
        al0 = *(const bfrag*)(Arl + kt);
        al1 = *(const bfrag*)(Arl + kt + 8);
      } else {
#pragma unroll
        for (int i = 0; i < 8; ++i) { ah0[i]=0; ah1[i]=0; al0[i]=0; al1[i]=0; }
      }
      const unsigned short* bp_h = Bph + (size_t)(bbase + (kt << 1)) * 8;
      const unsigned short* bp_l = Bpl + (size_t)(bbase + (kt << 1)) * 8;
      bfrag bh0 = *(const bfrag*)bp_h;
      bfrag bh1 = *(const bfrag*)(bp_h + 8);
      bfrag bl0 = *(const bfrag*)bp_l;
      bfrag bl1 = *(const bfrag*)(bp_l + 8);

      __syncthreads();
      {
        int q = a_h * 2;
        int i0 = ((a_m >> 4) * 64 + ((a_m & 15) | (q << 4))) * 8;
        int i1 = ((a_m >> 4) * 64 + ((a_m & 15) | ((q + 1) << 4))) * 8;
        *(bfrag*)&Ash[i0] = ah0;  *(bfrag*)&Ash[i1] = ah1;
        *(bfrag*)&Asl[i0] = al0;  *(bfrag*)&Asl[i1] = al1;
      }
      {
        int f0 = tid * 2;
        *(bfrag*)&Bsh[(size_t)f0 * 8] = bh0;
        *(bfrag*)&Bsh[(size_t)(f0 + 1) * 8] = bh1;
        *(bfrag*)&Bsl[(size_t)f0 * 8] = bl0;
        *(bfrag*)&Bsl[(size_t)(f0 + 1) * 8] = bl1;
      }
      __syncthreads();

      bfrag afh[4], afl[4], bfh[4], bfl[4];
#pragma unroll
      for (int mt = 0; mt < 4; ++mt) {
        int idx = ((wm * 4 + mt) * 64 + lane) * 8;
        afh[mt] = *(bfrag*)&Ash[idx];
        afl[mt] = *(bfrag*)&Asl[idx];
      }
#pragma unroll
      for (int nt = 0; nt < 4; ++nt) {
        int idx = ((wn * 4 + nt) * 64 + lane) * 8;
        bfh[nt] = *(bfrag*)&Bsh[idx];
        bfl[nt] = *(bfrag*)&Bsl[idx];
      }
#pragma unroll
      for (int mt = 0; mt < 4; ++mt)
#pragma unroll
        for (int nt = 0; nt < 4; ++nt) {
          acc[mt][nt] = __builtin_amdgcn_mfma_f32_16x16x32_bf16(afh[mt], bfh[nt], acc[mt][nt], 0, 0, 0);
          acc[mt][nt] = __builtin_amdgcn_mfma_f32_16x16x32_bf16(afh[mt], bfl[nt], acc[mt][nt], 0, 0, 0);
          acc[mt][nt] = __builtin_amdgcn_mfma_f32_16x16x32_bf16(afl[mt], bfh[nt], acc[mt][nt], 0, 0, 0);
        }
    }
  }

  // epilogue: C/D layout col=lane&15, row=(lane>>4)*4+reg   [m89-verified]
  const int cl = lane & 15;
  const int rq = lane >> 4;
#pragma unroll
  for (int mt = 0; mt < 4; ++mt)
#pragma unroll
    for (int r = 0; r < 4; ++r) {
      int row = row0 + wm * 64 + mt * 16 + rq * 4 + r;
      if (row < M) {
#pragma unroll
        for (int nt = 0; nt < 4; ++nt) {
          int colx = col0 + wn * 64 + nt * 16 + cl;
          float v = acc[mt][nt][r] * scale + (bias ? bias[colx] : 0.0f);
          if (do_relu) v = fmaxf(v, 0.0f);
          size_t o = (size_t)row * Nc + colx;
          if (Cf) Cf[o] = v;
          if (Ch) {
            unsigned short h, l; split2(v, h, l);
            Ch[o] = h; Cl[o] = l;
          }
        }
      }
    }
}

// ---------------------------------------------------------------------------
// GAT: wt[4][256] = {W@att_s(h0), W@att_s(h1), W@att_d(h0), W@att_d(h1)}
__global__ void k_wtilde(const float* __restrict__ gatW, const float* __restrict__ att_s,
                         const float* __restrict__ att_d, float* __restrict__ wt) {
  int k = threadIdx.x;
  const float* Wr = gatW + (size_t)k * 512;
  float s0 = 0, s1 = 0, d0 = 0, d1 = 0;
  for (int i = 0; i < 256; ++i) {
    float w0 = Wr[i], w1 = Wr[256 + i];
    s0 += w0 * att_s[i];       s1 += w1 * att_s[256 + i];
    d0 += w0 * att_d[i];       d1 += w1 * att_d[256 + i];
  }
  wt[k] = s0; wt[256 + k] = s1; wt[512 + k] = d0; wt[768 + k] = d1;
}

// per-node logits from xs planes
__global__ void k_al(const unsigned short* __restrict__ xsh_, const unsigned short* __restrict__ xsl_,
                     const float* __restrict__ wt,
                     float* __restrict__ al_s, float* __restrict__ al_d) {
  int node = blockIdx.x * 4 + (threadIdx.x >> 6);
  int lane = threadIdx.x & 63;
  if (node >= NN) return;
  size_t o = (size_t)node * 256 + lane * 4;
  ushort4 hv = *(const ushort4*)(xsh_ + o);
  ushort4 lv = *(const ushort4*)(xsl_ + o);
  float4 v = make_float4(join2(hv.x, lv.x), join2(hv.y, lv.y), join2(hv.z, lv.z), join2(hv.w, lv.w));
  const float4* w = (const float4*)wt;
  float4 a0 = w[lane], a1 = w[64 + lane], a2 = w[128 + lane], a3 = w[192 + lane];
  float s0 = v.x*a0.x + v.y*a0.y + v.z*a0.z + v.w*a0.w;
  float s1 = v.x*a1.x + v.y*a1.y + v.z*a1.z + v.w*a1.w;
  float s2 = v.x*a2.x + v.y*a2.y + v.z*a2.z + v.w*a2.w;
  float s3 = v.x*a3.x + v.y*a3.y + v.z*a3.z + v.w*a3.w;
  for (int off = 32; off; off >>= 1) {
    s0 += __shfl_down(s0, off); s1 += __shfl_down(s1, off);
    s2 += __shfl_down(s2, off); s3 += __shfl_down(s3, off);
  }
  if (lane == 0) {
    al_s[node*2] = s0; al_s[node*2 + 1] = s1;
    al_d[node*2] = s2; al_d[node*2 + 1] = s3;
  }
}

__device__ inline float lrelu(float v) { return v > 0.f ? v : 0.2f * v; }

// fused GAT softmax + aggregation over xs planes; writes AGG split planes
__global__ void k_gat_csr(const unsigned short* __restrict__ xsh_, const unsigned short* __restrict__ xsl_,
                          const int* __restrict__ rowptr, const int* __restrict__ srcs,
                          const float* __restrict__ als, const float* __restrict__ ald,
                          unsigned short* __restrict__ aggh, unsigned short* __restrict__ aggl) {
  int node = blockIdx.x * 4 + (threadIdx.x >> 6);
  int lane = threadIdx.x & 63;
  if (node >= NN) return;
  int p0 = rowptr[node], p1 = rowptr[node + 1];
  float bd0 = ald[node*2], bd1 = ald[node*2 + 1];
  float vs0 = lrelu(als[node*2] + bd0);
  float vs1 = lrelu(als[node*2 + 1] + bd1);
  float m0 = vs0, m1 = vs1;
  for (int p = p0; p < p1; ++p) {
    int s = srcs[p];
    float2 a = *(const float2*)(als + (size_t)s * 2);
    m0 = fmaxf(m0, lrelu(a.x + bd0));
    m1 = fmaxf(m1, lrelu(a.y + bd1));
  }
  float w0 = __expf(vs0 - m0), w1 = __expf(vs1 - m1);
  float den0 = w0, den1 = w1;
  size_t so = (size_t)node * 256 + lane * 4;
  ushort4 hv = *(const ushort4*)(xsh_ + so);
  ushort4 lv = *(const ushort4*)(xsl_ + so);
  float4 v = make_float4(join2(hv.x, lv.x), join2(hv.y, lv.y), join2(hv.z, lv.z), join2(hv.w, lv.w));
  float4 acc0 = make_float4(w0*v.x, w0*v.y, w0*v.z, w0*v.w);
  float4 acc1 = make_float4(w1*v.x, w1*v.y, w1*v.z, w1*v.w);
  int p = p0;
  int s = (p < p1) ? srcs[p] : 0;
  while (p < p1) {
    int sn = (p + 1 < p1) ? srcs[p + 1] : 0;
    float2 a = *(const float2*)(als + (size_t)s * 2);
    float e0 = __expf(lrelu(a.x + bd0) - m0);
    float e1 = __expf(lrelu(a.y + bd1) - m1);
    den0 += e0; den1 += e1;
    size_t eo = (size_t)s * 256 + lane * 4;
    ushort4 xh4 = *(const ushort4*)(xsh_ + eo);
    ushort4 xl4 = *(const ushort4*)(xsl_ + eo);
    float4 xv = make_float4(join2(xh4.x, xl4.x), join2(xh4.y, xl4.y),
                            join2(xh4.z, xl4.z), join2(xh4.w, xl4.w));
    acc0.x += e0*xv.x; acc0.y += e0*xv.y; acc0.z += e0*xv.z; acc0.w += e0*xv.w;
    acc1.x += e1*xv.x; acc1.y += e1*xv.y; acc1.z += e1*xv.z; acc1.w += e1*xv.w;
    s = sn; ++p;
  }
  float i0 = 1.0f / fmaxf(den0, 1e-16f);
  float i1 = 1.0f / fmaxf(den1, 1e-16f);
  ushort4 h, l;
  size_t o = (size_t)node * 512 + lane * 4;
  split2(acc0.x*i0, h.x, l.x); split2(acc0.y*i0, h.y, l.y);
  split2(acc0.z*i0, h.z, l.z); split2(acc0.w*i0, h.w, l.w);
  *(ushort4*)(aggh + o) = h; *(ushort4*)(aggl + o) = l;
  split2(acc1.x*i1, h.x, l.x); split2(acc1.y*i1, h.y, l.y);
  split2(acc1.z*i1, h.z, l.z); split2(acc1.w*i1, h.w, l.w);
  *(ushort4*)(aggh + o + 256) = h; *(ushort4*)(aggl + o + 256) = l;
}

// ---------------------------------------------------------------------------
// CSR RGCN aggregation for relations {rb, rb+1} from xt planes; accumulates
// into P3f; on final pass writes split planes instead.
__global__ void k_rgcn_csr(const unsigned short* __restrict__ xth, const unsigned short* __restrict__ xtl,
                           const int* __restrict__ rowptr, const int* __restrict__ srcs,
                           const int* __restrict__ ets, const int* __restrict__ cntrel,
                           float* __restrict__ P3f, int rb, int write_planes,
                           unsigned short* __restrict__ oh, unsigned short* __restrict__ ol) {
  int node = blockIdx.x * 4 + (threadIdx.x >> 6);
  int lane = threadIdx.x & 63;
  if (node >= NN) return;
  int p0 = rowptr[node], p1 = rowptr[node + 1];
  int c0 = cntrel[node * NREL + rb];
  int c1 = cntrel[node * NREL + rb + 1];
  float inv0 = c0 ? 1.0f / (float)c0 : 0.0f;
  float inv1 = c1 ? 1.0f / (float)c1 : 0.0f;
  float2 acc = ((const float2*)(P3f + ((size_t)node << 7)))[lane];
  for (int p = p0; p < p1; ++p) {
    unsigned rr = (unsigned)(ets[p] - rb);
    if (rr < 2u) {
      int s = srcs[p];
      size_t idx = (((size_t)rr * NN + s) << 7) + lane * 2;
      ushort2 hv = *(const ushort2*)(xth + idx);
      ushort2 lv = *(const ushort2*)(xtl + idx);
      float w = rr ? inv1 : inv0;
      acc.x += join2(hv.x, lv.x) * w;
      acc.y += join2(hv.y, lv.y) * w;
    }
  }
  if (write_planes) {
    ushort2 h, l;
    split2(acc.x, h.x, l.x); split2(acc.y, h.y, l.y);
    size_t o = ((size_t)node << 7) + lane * 2;
    *(ushort2*)(oh + o) = h;
    *(ushort2*)(ol + o) = l;
  } else {
    ((float2*)(P3f + ((size_t)node << 7)))[lane] = acc;
  }
}

// ---------------------------------------------------------------------------
__global__ void k_norm(float* __restrict__ out) {
  int gw = (int)(((long)blockIdx.x * blockDim.x + threadIdx.x) >> 6);
  int lane = threadIdx.x & 63;
  if (gw >= NN) return;
  float2* row = (float2*)(out + (size_t)gw * 128);
  float2 v = row[lane];
  float ss = v.x*v.x + v.y*v.y;
  for (int off = 32; off; off >>= 1) ss += __shfl_down(ss, off);
  ss = __shfl(ss, 0);
  float inv = 1.0f / fmaxf(sqrtf(ss), 1e-12f);
  row[lane] = make_float2(v.x*inv, v.y*inv);
}

// ---------------------------------------------------------------------------
extern "C" void kernel_launch(void* const* d_in, const int* in_sizes, int n_in,
                              void* d_out, int out_size, void* d_ws, size_t ws_size,
                              hipStream_t stream)
{
  const float* x     = (const float*)d_in[0];
  const int*   ei    = (const int*)d_in[1];
  const int*   etype = (const int*)d_in[2];
  const float* s1Wl  = (const float*)d_in[3];
  const float* s1Wr  = (const float*)d_in[4];
  const float* s1b   = (const float*)d_in[5];
  const float* s2Wl  = (const float*)d_in[6];
  const float* s2Wr  = (const float*)d_in[7];
  const float* s2b   = (const float*)d_in[8];
  const float* gatW  = (const float*)d_in[9];
  const float* att_s = (const float*)d_in[10];
  const float* att_d = (const float*)d_in[11];
  const float* gatb  = (const float*)d_in[12];
  const float* Wrel  = (const float*)d_in[13];
  const float* Wroot = (const float*)d_in[14];
  const float* rgcnb = (const float*)d_in[15];
  const float* fW    = (const float*)d_in[16];
  const float* fb    = (const float*)d_in[17];
  float* out = (float*)d_out;

  const int* src = ei;
  const int* dst = ei + NE;

  char* ws = (char*)d_ws;
  size_t off = 0;
  auto alloc = [&](size_t bytes) -> void* {
    void* p = ws + off;
    off = (off + bytes + 255) & ~(size_t)255;
    return p;
  };
  int*      deg    = (int*)alloc((size_t)NN * 4);
  int*      cntrel = (int*)alloc((size_t)NN * NREL * 4);
  int*      rowptr = (int*)alloc((size_t)(NN + 1) * 4);
  int*      cursor = (int*)alloc((size_t)NN * 4);
  int*      bsum   = (int*)alloc((size_t)NB * 4);
  int*      boff   = (int*)alloc((size_t)NB * 4);
  int*      srcs   = (int*)alloc((size_t)NE * 4);
  int*      ets    = (int*)alloc((size_t)NE * 4);
  float*    al_s   = (float*)alloc((size_t)NN * 2 * 4);
  float*    al_d   = (float*)alloc((size_t)NN * 2 * 4);
  float*    wt     = (float*)alloc((size_t)4 * 256 * 4);
  unsigned short* PBh = (unsigned short*)alloc((size_t)PK_TOTAL * 8 * 2);
  unsigned short* PBl = (unsigned short*)alloc((size_t)PK_TOTAL * 8 * 2);
  // 4 x 51.2 MB slabs with strict lifetime overlay (total ws ~216 MB)
  char* SAb = (char*)alloc((size_t)NN * 1024);
  char* SBb = (char*)alloc((size_t)NN * 1024);
  char* SCb = (char*)alloc((size_t)NN * 1024);
  char* SDb = (char*)alloc((size_t)NN * 1024);
  (void)ws_size; (void)in_sizes; (void)n_in; (void)out_size;

  // SlabA: phase1-2 x/m1 planes -> phase5-6 aggh -> phase7-9 P3f + p3 planes
  unsigned short* xh  = (unsigned short*)SAb;
  unsigned short* xl  = xh + (size_t)NN * 128;
  unsigned short* m1h = xl + (size_t)NN * 128;
  unsigned short* m1l = m1h + (size_t)NN * 128;
  unsigned short* aggh = (unsigned short*)SAb;                  // N*512
  float*          P3f  = (float*)SAb;                           // N*128 f32
  unsigned short* p3h  = (unsigned short*)(SAb + (size_t)NN * 512);
  unsigned short* p3l  = p3h + (size_t)NN * 128;
  // SlabB: x1 planes -> aggl -> xt planes (2 relations at a time)
  unsigned short* x1h = (unsigned short*)SBb;
  unsigned short* x1l = x1h + (size_t)NN * 256;
  unsigned short* aggl = (unsigned short*)SBb;                  // N*512
  unsigned short* xth = (unsigned short*)SBb;                   // 2*N*128
  unsigned short* xtl = xth + (size_t)NN * 256;
  // SlabC: m2 planes -> xg planes
  unsigned short* m2h = (unsigned short*)SCb;
  unsigned short* m2l = m2h + (size_t)NN * 256;
  unsigned short* xgh = (unsigned short*)SCb;
  unsigned short* xgl = xgh + (size_t)NN * 256;
  // SlabD: xs planes (persistent)
  unsigned short* xsh = (unsigned short*)SDb;
  unsigned short* xsl = xsh + (size_t)NN * 256;

  const int NODEB = (NN + 3) / 4;
  const int GY = (NN + 127) / 128;

  // ---- weight packing + CSR build
  k_pack<<<(PK_TOTAL + 255) / 256, 256, 0, stream>>>(s1Wl, s1Wr, s2Wl, s2Wr, gatW, Wrel, Wroot, fW, PBh, PBl);
  hipMemsetAsync(deg, 0, (size_t)NN * 4, stream);
  hipMemsetAsync(cntrel, 0, (size_t)NN * NREL * 4, stream);
  hipMemsetAsync(cursor, 0, (size_t)NN * 4, stream);
  k_counts<<<(NE + 255) / 256, 256, 0, stream>>>(src, dst, etype, deg, cntrel);
  k_scan1<<<NB, 256, 0, stream>>>(deg, bsum);
  k_scan2<<<1, 64, 0, stream>>>(bsum, boff, rowptr);
  k_scan3<<<NB, 256, 0, stream>>>(deg, boff, rowptr);
  k_fill<<<(NE + 255) / 256, 256, 0, stream>>>(src, dst, etype, rowptr, cursor, srcs, ets);
  k_split<<<((NN * 128 / 4) + 255) / 256, 256, 0, stream>>>(x, xh, xl, (long)NN * 128 / 4);

  // ---- SAGE1: mean(x) -> m1 ; x1 = relu([m1|x]@[Wl;Wr]+b) -> x1 planes
  k_mean128<<<NODEB, 256, 0, stream>>>(x, rowptr, srcs, m1h, m1l);
  k_gemm_mfma<<<dim3(2, GY, 1), 256, 0, stream>>>(PBh, PBl,
      m1h, m1l, 128, BF_S1WL, 128,  xh, xl, 128, BF_S1WR, 128,  nullptr, nullptr, 0, 0, 0,
      s1b, nullptr, x1h, x1l, NN, 256, 1.0f, 1, 0, 0);

  // ---- SAGE2: mean(x1) -> m2 ; x_sage -> xs planes
  k_mean256p<<<NODEB, 256, 0, stream>>>(x1h, x1l, rowptr, srcs, m2h, m2l);
  k_gemm_mfma<<<dim3(2, GY, 1), 256, 0, stream>>>(PBh, PBl,
      m2h, m2l, 256, BF_S2WL, 256,  x1h, x1l, 256, BF_S2WR, 256,  nullptr, nullptr, 0, 0, 0,
      s2b, nullptr, xsh, xsl, NN, 256, 1.0f, 1, 0, 0);

  // ---- GAT: logits, fused softmax+aggregation, projection
  k_wtilde<<<1, 256, 0, stream>>>(gatW, att_s, att_d, wt);
  k_al<<<NODEB, 256, 0, stream>>>(xsh, xsl, wt, al_s, al_d);
  k_gat_csr<<<NODEB, 256, 0, stream>>>(xsh, xsl, rowptr, srcs, al_s, al_d, aggh, aggl);
  k_gemm_mfma<<<dim3(2, GY, 1), 256, 0, stream>>>(PBh, PBl,
      aggh, aggl, 512, BF_GATW0, 256,  aggh + 256, aggl + 256, 512, BF_GATW1, 256,
      nullptr, nullptr, 0, 0, 0,
      gatb, nullptr, xgh, xgl, NN, 256, 0.5f, 1, 0, 0);

  // ---- RGCN: root -> P3f ; relations in 2 batches of 2 (xt reuses SlabB)
  k_gemm_mfma<<<dim3(1, GY, 1), 256, 0, stream>>>(PBh, PBl,
      xgh, xgl, 256, BF_WROOT, 256,  nullptr, nullptr, 0, 0, 0,  nullptr, nullptr, 0, 0, 0,
      rgcnb, P3f, nullptr, nullptr, NN, 128, 1.0f, 0, 0, 0);
  k_gemm_mfma<<<dim3(1, GY, 2), 256, 0, stream>>>(PBh, PBl,
      xgh, xgl, 256, BF_WREL, 256,  nullptr, nullptr, 0, 0, 0,  nullptr, nullptr, 0, 0, 0,
      nullptr, nullptr, xth, xtl, NN, 128, 1.0f, 0, 4096, (long)NN * 128);
  k_rgcn_csr<<<NODEB, 256, 0, stream>>>(xth, xtl, rowptr, srcs, ets, cntrel, P3f, 0, 0, nullptr, nullptr);
  k_gemm_mfma<<<dim3(1, GY, 2), 256, 0, stream>>>(PBh, PBl,
      xgh, xgl, 256, BF_WREL + 8192, 256,  nullptr, nullptr, 0, 0, 0,  nullptr, nullptr, 0, 0, 0,
      nullptr, nullptr, xth, xtl, NN, 128, 1.0f, 0, 4096, (long)NN * 128);
  k_rgcn_csr<<<NODEB, 256, 0, stream>>>(xth, xtl, rowptr, srcs, ets, cntrel, P3f, 2, 1, p3h, p3l);

  // ---- fusion + L2 normalize
  k_gemm_mfma<<<dim3(1, GY, 1), 256, 0, stream>>>(PBh, PBl,
      xsh, xsl, 256, BF_FW0, 256,  xgh, xgl, 256, BF_FW1, 256,  p3h, p3l, 128, BF_FW2, 128,
      fb, out, nullptr, nullptr, NN, 128, 1.0f, 0, 0, 0);
  k_norm<<<(NN + 3) / 4, 256, 0, stream>>>(out);
}

// Round 6
// 1094.150 us; speedup vs baseline: 3.0380x; 1.1619x over previous
//
#include <hip/hip_runtime.h>
#include <math.h>

constexpr int NN   = 50000;
constexpr int NE   = 800000;
constexpr int NREL = 4;
constexpr int NB   = (NN + 255) / 256;   // scan blocks

typedef __attribute__((ext_vector_type(8))) short bfrag;     // 8 bf16 (4 VGPRs)
typedef __attribute__((ext_vector_type(4))) float floatx4;   // MFMA acc

__device__ inline unsigned short bf16_rne(float x) {
  unsigned u = __float_as_uint(x);
  unsigned r = (u + 0x7FFFu + ((u >> 16) & 1u)) >> 16;
  return (unsigned short)r;
}
__device__ inline float bf2f(unsigned short h) {
  return __uint_as_float((unsigned)h << 16);
}
// RNE hi + exact-ish residual lo (hi-only readers get unbiased 2^-10 rounding)
__device__ inline void split2(float x, unsigned short& h, unsigned short& l) {
  h = bf16_rne(x);
  l = bf16_rne(x - bf2f(h));
}
__device__ inline float join2(unsigned short h, unsigned short l) {
  return bf2f(h) + bf2f(l);
}

// ---------------------------------------------------------------------------
__global__ void k_counts(const int* __restrict__ src, const int* __restrict__ dst,
                         const int* __restrict__ et, int* deg, int* cntrel) {
  int e = blockIdx.x * blockDim.x + threadIdx.x;
  if (e < NE) {
    int d = dst[e];
    atomicAdd(&deg[d], 1);
    atomicAdd(&cntrel[d * NREL + et[e]], 1);
  }
}

__global__ void k_scan1(const int* __restrict__ deg, int* bsum) {
  __shared__ int sm[256];
  int i = blockIdx.x * 256 + threadIdx.x;
  sm[threadIdx.x] = (i < NN) ? deg[i] : 0;
  __syncthreads();
  for (int s = 128; s; s >>= 1) {
    if (threadIdx.x < s) sm[threadIdx.x] += sm[threadIdx.x + s];
    __syncthreads();
  }
  if (threadIdx.x == 0) bsum[blockIdx.x] = sm[0];
}
__global__ void k_scan2(const int* __restrict__ bsum, int* boff, int* rowptr) {
  if (threadIdx.x == 0 && blockIdx.x == 0) {
    int acc = 0;
    for (int b = 0; b < NB; ++b) { boff[b] = acc; acc += bsum[b]; }
    rowptr[NN] = NE;
  }
}
__global__ void k_scan3(const int* __restrict__ deg, const int* __restrict__ boff,
                        int* rowptr) {
  __shared__ int sm[256];
  int i = blockIdx.x * 256 + threadIdx.x;
  int v = (i < NN) ? deg[i] : 0;
  sm[threadIdx.x] = v;
  __syncthreads();
  for (int s = 1; s < 256; s <<= 1) {
    int t = (threadIdx.x >= s) ? sm[threadIdx.x - s] : 0;
    __syncthreads();
    sm[threadIdx.x] += t;
    __syncthreads();
  }
  if (i < NN) rowptr[i] = boff[blockIdx.x] + sm[threadIdx.x] - v;  // exclusive
}

__global__ void k_fill(const int* __restrict__ src, const int* __restrict__ dst,
                       const int* __restrict__ et, const int* __restrict__ rowptr,
                       int* cursor, int* srcs, int* ets) {
  int e = blockIdx.x * blockDim.x + threadIdx.x;
  if (e >= NE) return;
  int d = dst[e];
  int pos = rowptr[d] + atomicAdd(&cursor[d], 1);
  srcs[pos] = src[e];
  ets[pos]  = et[e];
}

// ---------------------------------------------------------------------------
// weight packing into MFMA fragment order (bf16 hi only), once per launch.
#define PK_N 14
__device__ __constant__ const int PK_BASE[PK_N]  = {0,1,2,3,4,4,5,5,5,5,6,7,7,7};
__device__ __constant__ const int PK_EOFF[PK_N]  = {0,0,0,0,0,256,0,32768,65536,98304,0,0,32768,65536};
__device__ __constant__ const int PK_K[PK_N]     = {128,128,256,256,256,256,256,256,256,256,256,256,256,128};
__device__ __constant__ const int PK_LDB[PK_N]   = {256,256,256,256,512,512,128,128,128,128,128,128,128,128};
__device__ __constant__ const int PK_START[PK_N] = {0,4096,8192,16384,24576,32768,40960,45056,49152,53248,57344,61440,65536,69632};
constexpr int PK_TOTAL = 71680;
constexpr int BF_S1WL = 0,     BF_S1WR = 4096,  BF_S2WL = 8192,  BF_S2WR = 16384;
constexpr int BF_GATW0 = 24576, BF_GATW1 = 32768, BF_WREL = 40960, BF_WROOT = 57344;
constexpr int BF_FW0 = 61440,  BF_FW1 = 65536,  BF_FW2 = 69632;

__global__ void k_pack(const float* b0, const float* b1, const float* b2, const float* b3,
                       const float* b4, const float* b5, const float* b6, const float* b7,
                       unsigned short* __restrict__ Bh) {
  int f = blockIdx.x * 256 + threadIdx.x;
  if (f >= PK_TOTAL) return;
  int m = 0;
#pragma unroll
  for (int i = 1; i < PK_N; ++i) if (f >= PK_START[i]) m = i;
  const float* bases[8] = {b0,b1,b2,b3,b4,b5,b6,b7};
  int lf = f - PK_START[m];
  int K = PK_K[m], ldb = PK_LDB[m];
  int Kq16 = K << 1;
  int ntile = lf / Kq16;
  int rem = lf - ntile * Kq16;
  int kq = rem >> 4, c = rem & 15;
  const float* sp = bases[PK_BASE[m]] + PK_EOFF[m] + (size_t)(kq * 8) * ldb + ntile * 16 + c;
#pragma unroll
  for (int j = 0; j < 8; ++j)
    Bh[(size_t)f * 8 + j] = bf16_rne(sp[(size_t)j * ldb]);
}

// x -> hi/lo planes
__global__ void k_split(const float* __restrict__ x, unsigned short* __restrict__ xh,
                        unsigned short* __restrict__ xl, long total4) {
  long i = (long)blockIdx.x * blockDim.x + threadIdx.x;
  if (i >= total4) return;
  float4 v = ((const float4*)x)[i];
  ushort4 h, l;
  split2(v.x, h.x, l.x); split2(v.y, h.y, l.y);
  split2(v.z, h.z, l.z); split2(v.w, h.w, l.w);
  ((ushort4*)xh)[i] = h;
  ((ushort4*)xl)[i] = l;
}

// ---------------------------------------------------------------------------
// CSR mean, 128 ch, reads hi plane only, writes split planes
__global__ void k_mean128p(const unsigned short* __restrict__ ih, const int* __restrict__ rowptr,
                           const int* __restrict__ srcs,
                           unsigned short* __restrict__ oh, unsigned short* __restrict__ ol) {
  int node = blockIdx.x * 4 + (threadIdx.x >> 6);
  int lane = threadIdx.x & 63;
  if (node >= NN) return;
  int p0 = rowptr[node], p1 = rowptr[node + 1];
  float2 acc = make_float2(0.f, 0.f);
  int p = p0;
  int s = (p < p1) ? srcs[p] : 0;
  while (p < p1) {
    int sn = (p + 1 < p1) ? srcs[p + 1] : 0;
    ushort2 hv = ((const ushort2*)(ih + ((size_t)s << 7)))[lane];
    acc.x += bf2f(hv.x); acc.y += bf2f(hv.y);
    s = sn; ++p;
  }
  float inv = (p1 > p0) ? 1.0f / (float)(p1 - p0) : 0.0f;
  ushort2 h, l;
  split2(acc.x * inv, h.x, l.x); split2(acc.y * inv, h.y, l.y);
  size_t o = ((size_t)node << 7) + lane * 2;
  *(ushort2*)(oh + o) = h;
  *(ushort2*)(ol + o) = l;
}

// CSR mean, 256 ch, reads hi plane only, writes split planes
__global__ void k_mean256p(const unsigned short* __restrict__ ih, const int* __restrict__ rowptr,
                           const int* __restrict__ srcs,
                           unsigned short* __restrict__ oh, unsigned short* __restrict__ ol) {
  int node = blockIdx.x * 4 + (threadIdx.x >> 6);
  int lane = threadIdx.x & 63;
  if (node >= NN) return;
  int p0 = rowptr[node], p1 = rowptr[node + 1];
  float4 acc = make_float4(0.f, 0.f, 0.f, 0.f);
  int p = p0;
  int s = (p < p1) ? srcs[p] : 0;
  while (p < p1) {
    int sn = (p + 1 < p1) ? srcs[p + 1] : 0;
    ushort4 hv = *(const ushort4*)(ih + ((size_t)s << 8) + lane * 4);
    acc.x += bf2f(hv.x); acc.y += bf2f(hv.y);
    acc.z += bf2f(hv.z); acc.w += bf2f(hv.w);
    s = sn; ++p;
  }
  float inv = (p1 > p0) ? 1.0f / (float)(p1 - p0) : 0.0f;
  ushort4 h, l;
  split2(acc.x * inv, h.x, l.x); split2(acc.y * inv, h.y, l.y);
  split2(acc.z * inv, h.z, l.z); split2(acc.w * inv, h.w, l.w);
  size_t o = ((size_t)node << 8) + lane * 4;
  *(ushort4*)(oh + o) = h;
  *(ushort4*)(ol + o) = l;
}

// ---------------------------------------------------------------------------
// split-A x bf16-B MFMA GEMM (2 MFMAs per tile pair): A split hi/lo planes,
// B packed fragments (bf16). C = scale*(sum_p A_p B_p) + bias (+relu).
__global__ __launch_bounds__(256)
void k_gemm_mfma(const unsigned short* __restrict__ Bph,
                 const unsigned short* A0h, const unsigned short* A0l, int lda0, int bf0, int K0,
                 const unsigned short* A1h, const unsigned short* A1l, int lda1, int bf1, int K1,
                 const unsigned short* A2h, const unsigned short* A2l, int lda2, int bf2, int K2,
                 const float* __restrict__ bias, float* Cf,
                 unsigned short* Ch, unsigned short* Cl,
                 int M, int Nc, float scale, int do_relu, int zsB, long zsC)
{
  __shared__ short Ash[8*64*8], Asl[8*64*8], Bsh[8*64*8];
  const int tid  = threadIdx.x;
  const int lane = tid & 63;
  const int wv   = tid >> 6;
  const int wm   = wv >> 1, wn = wv & 1;
  const int row0 = blockIdx.y * 128;
  const int col0 = blockIdx.x * 128;
  if (zsB) {
    bf0 += blockIdx.z * zsB;
    long zc = (long)blockIdx.z * zsC;
    if (Cf) Cf += zc;
    if (Ch) { Ch += zc; if (Cl) Cl += zc; }
  }

  floatx4 acc[4][4];
#pragma unroll
  for (int i = 0; i < 4; ++i)
#pragma unroll
    for (int j = 0; j < 4; ++j) acc[i][j] = 0;

  const int a_m = tid >> 1;
  const int a_h = tid & 1;
  const int b_nt = tid >> 5;
  const int b_rem = (tid << 1) & 63;

  const unsigned short* Aharr[3] = {A0h, A1h, A2h};
  const unsigned short* Alarr[3] = {A0l, A1l, A2l};
  const int ldaArr[3] = {lda0, lda1, lda2};
  const int bfArr[3]  = {bf0, bf1, bf2};
  const int Karr[3]   = {K0, K1, K2};

  for (int p = 0; p < 3; ++p) {
    const int K = Karr[p];
    if (K == 0) continue;
    const int lda = ldaArr[p];
    const bool arow_ok = (row0 + a_m) < M;
    const unsigned short* Arh = Aharr[p] + (size_t)(row0 + a_m) * lda + a_h * 16;
    const unsigned short* Arl = Alarr[p] + (size_t)(row0 + a_m) * lda + a_h * 16;
    const int Kq16 = K << 1;
    const int bbase = bfArr[p] + (col0 >> 4) * Kq16 + b_nt * Kq16 + b_rem;

    for (int kt = 0; kt < K; kt += 32) {
      bfrag ah0, ah1, al0, al1;
      if (arow_ok) {
        ah0 = *(const bfrag*)(Arh + kt);
        ah1 = *(const bfrag*)(Arh + kt + 8);
        al0 = *(const bfrag*)(Arl + kt);
        al1 = *(const bfrag*)(Arl + kt + 8);
      } else {
#pragma unroll
        for (int i = 0; i < 8; ++i) { ah0[i]=0; ah1[i]=0; al0[i]=0; al1[i]=0; }
      }
      const unsigned short* bp_h = Bph + (size_t)(bbase + (kt << 1)) * 8;
      bfrag bh0 = *(const bfrag*)bp_h;
      bfrag bh1 = *(const bfrag*)(bp_h + 8);

      __syncthreads();
      {
        int q = a_h * 2;
        int i0 = ((a_m >> 4) * 64 + ((a_m & 15) | (q << 4))) * 8;
        int i1 = ((a_m >> 4) * 64 + ((a_m & 15) | ((q + 1) << 4))) * 8;
        *(bfrag*)&Ash[i0] = ah0;  *(bfrag*)&Ash[i1] = ah1;
        *(bfrag*)&Asl[i0] = al0;  *(bfrag*)&Asl[i1] = al1;
      }
      {
        int f0 = tid * 2;
        *(bfrag*)&Bsh[(size_t)f0 * 8] = bh0;
        *(bfrag*)&Bsh[(size_t)(f0 + 1) * 8] = bh1;
      }
      __syncthreads();

      bfrag afh[4], afl[4], bfh[4];
#pragma unroll
      for (int mt = 0; mt < 4; ++mt) {
        int idx = ((wm * 4 + mt) * 64 + lane) * 8;
        afh[mt] = *(bfrag*)&Ash[idx];
        afl[mt] = *(bfrag*)&Asl[idx];
      }
#pragma unroll
      for (int nt = 0; nt < 4; ++nt) {
        int idx = ((wn * 4 + nt) * 64 + lane) * 8;
        bfh[nt] = *(bfrag*)&Bsh[idx];
      }
#pragma unroll
      for (int mt = 0; mt < 4; ++mt)
#pragma unroll
        for (int nt = 0; nt < 4; ++nt) {
          acc[mt][nt] = __builtin_amdgcn_mfma_f32_16x16x32_bf16(afh[mt], bfh[nt], acc[mt][nt], 0, 0, 0);
          acc[mt][nt] = __builtin_amdgcn_mfma_f32_16x16x32_bf16(afl[mt], bfh[nt], acc[mt][nt], 0, 0, 0);
        }
    }
  }

  // epilogue: C/D layout col=lane&15, row=(lane>>4)*4+reg   [m89-verified]
  const int cl = lane & 15;
  const int rq = lane >> 4;
#pragma unroll
  for (int mt = 0; mt < 4; ++mt)
#pragma unroll
    for (int r = 0; r < 4; ++r) {
      int row = row0 + wm * 64 + mt * 16 + rq * 4 + r;
      if (row < M) {
#pragma unroll
        for (int nt = 0; nt < 4; ++nt) {
          int colx = col0 + wn * 64 + nt * 16 + cl;
          float v = acc[mt][nt][r] * scale + (bias ? bias[colx] : 0.0f);
          if (do_relu) v = fmaxf(v, 0.0f);
          size_t o = (size_t)row * Nc + colx;
          if (Cf) Cf[o] = v;
          if (Ch) {
            if (Cl) {
              unsigned short h, l; split2(v, h, l);
              Ch[o] = h; Cl[o] = l;
            } else {
              Ch[o] = bf16_rne(v);
            }
          }
        }
      }
    }
}

// ---------------------------------------------------------------------------
// GAT: wt[4][256] = {W@att_s(h0), W@att_s(h1), W@att_d(h0), W@att_d(h1)}
__global__ void k_wtilde(const float* __restrict__ gatW, const float* __restrict__ att_s,
                         const float* __restrict__ att_d, float* __restrict__ wt) {
  int k = threadIdx.x;
  const float* Wr = gatW + (size_t)k * 512;
  float s0 = 0, s1 = 0, d0 = 0, d1 = 0;
  for (int i = 0; i < 256; ++i) {
    float w0 = Wr[i], w1 = Wr[256 + i];
    s0 += w0 * att_s[i];       s1 += w1 * att_s[256 + i];
    d0 += w0 * att_d[i];       d1 += w1 * att_d[256 + i];
  }
  wt[k] = s0; wt[256 + k] = s1; wt[512 + k] = d0; wt[768 + k] = d1;
}

// per-node logits from xs hi plane
__global__ void k_al(const unsigned short* __restrict__ xsh_, const float* __restrict__ wt,
                     float* __restrict__ al_s, float* __restrict__ al_d) {
  int node = blockIdx.x * 4 + (threadIdx.x >> 6);
  int lane = threadIdx.x & 63;
  if (node >= NN) return;
  ushort4 hv = *(const ushort4*)(xsh_ + (size_t)node * 256 + lane * 4);
  float4 v = make_float4(bf2f(hv.x), bf2f(hv.y), bf2f(hv.z), bf2f(hv.w));
  const float4* w = (const float4*)wt;
  float4 a0 = w[lane], a1 = w[64 + lane], a2 = w[128 + lane], a3 = w[192 + lane];
  float s0 = v.x*a0.x + v.y*a0.y + v.z*a0.z + v.w*a0.w;
  float s1 = v.x*a1.x + v.y*a1.y + v.z*a1.z + v.w*a1.w;
  float s2 = v.x*a2.x + v.y*a2.y + v.z*a2.z + v.w*a2.w;
  float s3 = v.x*a3.x + v.y*a3.y + v.z*a3.z + v.w*a3.w;
  for (int off = 32; off; off >>= 1) {
    s0 += __shfl_down(s0, off); s1 += __shfl_down(s1, off);
    s2 += __shfl_down(s2, off); s3 += __shfl_down(s3, off);
  }
  if (lane == 0) {
    al_s[node*2] = s0; al_s[node*2 + 1] = s1;
    al_d[node*2] = s2; al_d[node*2 + 1] = s3;
  }
}

__device__ inline float lrelu(float v) { return v > 0.f ? v : 0.2f * v; }

// fused GAT softmax + aggregation over xs hi plane; writes AGG split planes
__global__ void k_gat_csr(const unsigned short* __restrict__ xsh_,
                          const int* __restrict__ rowptr, const int* __restrict__ srcs,
                          const float* __restrict__ als, const float* __restrict__ ald,
                          unsigned short* __restrict__ aggh, unsigned short* __restrict__ aggl) {
  int node = blockIdx.x * 4 + (threadIdx.x >> 6);
  int lane = threadIdx.x & 63;
  if (node >= NN) return;
  int p0 = rowptr[node], p1 = rowptr[node + 1];
  float bd0 = ald[node*2], bd1 = ald[node*2 + 1];
  float vs0 = lrelu(als[node*2] + bd0);
  float vs1 = lrelu(als[node*2 + 1] + bd1);
  float m0 = vs0, m1 = vs1;
  for (int p = p0; p < p1; ++p) {
    int s = srcs[p];
    float2 a = *(const float2*)(als + (size_t)s * 2);
    m0 = fmaxf(m0, lrelu(a.x + bd0));
    m1 = fmaxf(m1, lrelu(a.y + bd1));
  }
  float w0 = __expf(vs0 - m0), w1 = __expf(vs1 - m1);
  float den0 = w0, den1 = w1;
  ushort4 hv = *(const ushort4*)(xsh_ + (size_t)node * 256 + lane * 4);
  float4 v = make_float4(bf2f(hv.x), bf2f(hv.y), bf2f(hv.z), bf2f(hv.w));
  float4 acc0 = make_float4(w0*v.x, w0*v.y, w0*v.z, w0*v.w);
  float4 acc1 = make_float4(w1*v.x, w1*v.y, w1*v.z, w1*v.w);
  int p = p0;
  int s = (p < p1) ? srcs[p] : 0;
  while (p < p1) {
    int sn = (p + 1 < p1) ? srcs[p + 1] : 0;
    float2 a = *(const float2*)(als + (size_t)s * 2);
    float e0 = __expf(lrelu(a.x + bd0) - m0);
    float e1 = __expf(lrelu(a.y + bd1) - m1);
    den0 += e0; den1 += e1;
    ushort4 xh4 = *(const ushort4*)(xsh_ + (size_t)s * 256 + lane * 4);
    float4 xv = make_float4(bf2f(xh4.x), bf2f(xh4.y), bf2f(xh4.z), bf2f(xh4.w));
    acc0.x += e0*xv.x; acc0.y += e0*xv.y; acc0.z += e0*xv.z; acc0.w += e0*xv.w;
    acc1.x += e1*xv.x; acc1.y += e1*xv.y; acc1.z += e1*xv.z; acc1.w += e1*xv.w;
    s = sn; ++p;
  }
  float i0 = 1.0f / fmaxf(den0, 1e-16f);
  float i1 = 1.0f / fmaxf(den1, 1e-16f);
  ushort4 h, l;
  size_t o = (size_t)node * 512 + lane * 4;
  split2(acc0.x*i0, h.x, l.x); split2(acc0.y*i0, h.y, l.y);
  split2(acc0.z*i0, h.z, l.z); split2(acc0.w*i0, h.w, l.w);
  *(ushort4*)(aggh + o) = h; *(ushort4*)(aggl + o) = l;
  split2(acc1.x*i1, h.x, l.x); split2(acc1.y*i1, h.y, l.y);
  split2(acc1.z*i1, h.z, l.z); split2(acc1.w*i1, h.w, l.w);
  *(ushort4*)(aggh + o + 256) = h; *(ushort4*)(aggl + o + 256) = l;
}

// ---------------------------------------------------------------------------
// CSR RGCN aggregation, all 4 relations, xt hi plane only; base P3f; writes planes
__global__ void k_rgcn_csr(const unsigned short* __restrict__ xth,
                           const int* __restrict__ rowptr, const int* __restrict__ srcs,
                           const int* __restrict__ ets, const int* __restrict__ cntrel,
                           const float* __restrict__ P3f,
                           unsigned short* __restrict__ oh, unsigned short* __restrict__ ol) {
  int node = blockIdx.x * 4 + (threadIdx.x >> 6);
  int lane = threadIdx.x & 63;
  if (node >= NN) return;
  int p0 = rowptr[node], p1 = rowptr[node + 1];
  float inv0, inv1, inv2, inv3;
  {
    int c0 = cntrel[node*NREL], c1 = cntrel[node*NREL+1];
    int c2 = cntrel[node*NREL+2], c3 = cntrel[node*NREL+3];
    inv0 = c0 ? 1.0f/(float)c0 : 0.0f;  inv1 = c1 ? 1.0f/(float)c1 : 0.0f;
    inv2 = c2 ? 1.0f/(float)c2 : 0.0f;  inv3 = c3 ? 1.0f/(float)c3 : 0.0f;
  }
  float2 acc = ((const float2*)(P3f + ((size_t)node << 7)))[lane];
  int p = p0;
  int s = 0, r = 0;
  if (p < p1) { s = srcs[p]; r = ets[p]; }
  while (p < p1) {
    int sn = 0, rn = 0;
    if (p + 1 < p1) { sn = srcs[p + 1]; rn = ets[p + 1]; }
    ushort2 hv = *(const ushort2*)(xth + (((size_t)r * NN + s) << 7) + lane * 2);
    float w = (r == 0) ? inv0 : (r == 1) ? inv1 : (r == 2) ? inv2 : inv3;
    acc.x += bf2f(hv.x) * w;
    acc.y += bf2f(hv.y) * w;
    s = sn; r = rn; ++p;
  }
  ushort2 h, l;
  split2(acc.x, h.x, l.x); split2(acc.y, h.y, l.y);
  size_t o = ((size_t)node << 7) + lane * 2;
  *(ushort2*)(oh + o) = h;
  *(ushort2*)(ol + o) = l;
}

// ---------------------------------------------------------------------------
__global__ void k_norm(float* __restrict__ out) {
  int gw = (int)(((long)blockIdx.x * blockDim.x + threadIdx.x) >> 6);
  int lane = threadIdx.x & 63;
  if (gw >= NN) return;
  float2* row = (float2*)(out + (size_t)gw * 128);
  float2 v = row[lane];
  float ss = v.x*v.x + v.y*v.y;
  for (int off = 32; off; off >>= 1) ss += __shfl_down(ss, off);
  ss = __shfl(ss, 0);
  float inv = 1.0f / fmaxf(sqrtf(ss), 1e-12f);
  row[lane] = make_float2(v.x*inv, v.y*inv);
}

// ---------------------------------------------------------------------------
extern "C" void kernel_launch(void* const* d_in, const int* in_sizes, int n_in,
                              void* d_out, int out_size, void* d_ws, size_t ws_size,
                              hipStream_t stream)
{
  const float* x     = (const float*)d_in[0];
  const int*   ei    = (const int*)d_in[1];
  const int*   etype = (const int*)d_in[2];
  const float* s1Wl  = (const float*)d_in[3];
  const float* s1Wr  = (const float*)d_in[4];
  const float* s1b   = (const float*)d_in[5];
  const float* s2Wl  = (const float*)d_in[6];
  const float* s2Wr  = (const float*)d_in[7];
  const float* s2b   = (const float*)d_in[8];
  const float* gatW  = (const float*)d_in[9];
  const float* att_s = (const float*)d_in[10];
  const float* att_d = (const float*)d_in[11];
  const float* gatb  = (const float*)d_in[12];
  const float* Wrel  = (const float*)d_in[13];
  const float* Wroot = (const float*)d_in[14];
  const float* rgcnb = (const float*)d_in[15];
  const float* fW    = (const float*)d_in[16];
  const float* fb    = (const float*)d_in[17];
  float* out = (float*)d_out;

  const int* src = ei;
  const int* dst = ei + NE;

  char* ws = (char*)d_ws;
  size_t off = 0;
  auto alloc = [&](size_t bytes) -> void* {
    void* p = ws + off;
    off = (off + bytes + 255) & ~(size_t)255;
    return p;
  };
  int*      deg    = (int*)alloc((size_t)NN * 4);
  int*      cntrel = (int*)alloc((size_t)NN * NREL * 4);
  int*      rowptr = (int*)alloc((size_t)(NN + 1) * 4);
  int*      cursor = (int*)alloc((size_t)NN * 4);
  int*      bsum   = (int*)alloc((size_t)NB * 4);
  int*      boff   = (int*)alloc((size_t)NB * 4);
  int*      srcs   = (int*)alloc((size_t)NE * 4);
  int*      ets    = (int*)alloc((size_t)NE * 4);
  float*    al_s   = (float*)alloc((size_t)NN * 2 * 4);
  float*    al_d   = (float*)alloc((size_t)NN * 2 * 4);
  float*    wt     = (float*)alloc((size_t)4 * 256 * 4);
  unsigned short* PBh = (unsigned short*)alloc((size_t)PK_TOTAL * 8 * 2);
  // 4 x 51.2 MB slabs with strict lifetime overlay (total ws ~215 MB)
  char* SAb = (char*)alloc((size_t)NN * 1024);
  char* SBb = (char*)alloc((size_t)NN * 1024);
  char* SCb = (char*)alloc((size_t)NN * 1024);
  char* SDb = (char*)alloc((size_t)NN * 1024);
  (void)ws_size; (void)in_sizes; (void)n_in; (void)out_size;

  // SlabA: x/m1 planes -> aggh -> P3f + p3 planes
  unsigned short* xh  = (unsigned short*)SAb;
  unsigned short* xl  = xh + (size_t)NN * 128;
  unsigned short* m1h = xl + (size_t)NN * 128;
  unsigned short* m1l = m1h + (size_t)NN * 128;
  unsigned short* aggh = (unsigned short*)SAb;                  // N*512
  float*          P3f  = (float*)SAb;                           // N*128 f32
  unsigned short* p3h  = (unsigned short*)(SAb + (size_t)NN * 512);
  unsigned short* p3l  = p3h + (size_t)NN * 128;
  // SlabB: x1 planes -> aggl -> xt hi (4 relations)
  unsigned short* x1h = (unsigned short*)SBb;
  unsigned short* x1l = x1h + (size_t)NN * 256;
  unsigned short* aggl = (unsigned short*)SBb;                  // N*512
  unsigned short* xth = (unsigned short*)SBb;                   // 4*N*128
  // SlabC: m2 planes -> xg planes
  unsigned short* m2h = (unsigned short*)SCb;
  unsigned short* m2l = m2h + (size_t)NN * 256;
  unsigned short* xgh = (unsigned short*)SCb;
  unsigned short* xgl = xgh + (size_t)NN * 256;
  // SlabD: xs planes (persistent)
  unsigned short* xsh = (unsigned short*)SDb;
  unsigned short* xsl = xsh + (size_t)NN * 256;

  const int NODEB = (NN + 3) / 4;
  const int GY = (NN + 127) / 128;

  // ---- weight packing + CSR build
  k_pack<<<(PK_TOTAL + 255) / 256, 256, 0, stream>>>(s1Wl, s1Wr, s2Wl, s2Wr, gatW, Wrel, Wroot, fW, PBh);
  hipMemsetAsync(deg, 0, (size_t)NN * 4, stream);
  hipMemsetAsync(cntrel, 0, (size_t)NN * NREL * 4, stream);
  hipMemsetAsync(cursor, 0, (size_t)NN * 4, stream);
  k_counts<<<(NE + 255) / 256, 256, 0, stream>>>(src, dst, etype, deg, cntrel);
  k_scan1<<<NB, 256, 0, stream>>>(deg, bsum);
  k_scan2<<<1, 64, 0, stream>>>(bsum, boff, rowptr);
  k_scan3<<<NB, 256, 0, stream>>>(deg, boff, rowptr);
  k_fill<<<(NE + 255) / 256, 256, 0, stream>>>(src, dst, etype, rowptr, cursor, srcs, ets);
  k_split<<<((NN * 128 / 4) + 255) / 256, 256, 0, stream>>>(x, xh, xl, (long)NN * 128 / 4);

  // ---- SAGE1: mean(x hi) -> m1 ; x1 = relu([m1|x]@[Wl;Wr]+b) -> x1 planes
  k_mean128p<<<NODEB, 256, 0, stream>>>(xh, rowptr, srcs, m1h, m1l);
  k_gemm_mfma<<<dim3(2, GY, 1), 256, 0, stream>>>(PBh,
      m1h, m1l, 128, BF_S1WL, 128,  xh, xl, 128, BF_S1WR, 128,  nullptr, nullptr, 0, 0, 0,
      s1b, nullptr, x1h, x1l, NN, 256, 1.0f, 1, 0, 0);

  // ---- SAGE2: mean(x1 hi) -> m2 ; x_sage -> xs planes
  k_mean256p<<<NODEB, 256, 0, stream>>>(x1h, rowptr, srcs, m2h, m2l);
  k_gemm_mfma<<<dim3(2, GY, 1), 256, 0, stream>>>(PBh,
      m2h, m2l, 256, BF_S2WL, 256,  x1h, x1l, 256, BF_S2WR, 256,  nullptr, nullptr, 0, 0, 0,
      s2b, nullptr, xsh, xsl, NN, 256, 1.0f, 1, 0, 0);

  // ---- GAT: logits, fused softmax+aggregation, projection
  k_wtilde<<<1, 256, 0, stream>>>(gatW, att_s, att_d, wt);
  k_al<<<NODEB, 256, 0, stream>>>(xsh, wt, al_s, al_d);
  k_gat_csr<<<NODEB, 256, 0, stream>>>(xsh, rowptr, srcs, al_s, al_d, aggh, aggl);
  k_gemm_mfma<<<dim3(2, GY, 1), 256, 0, stream>>>(PBh,
      aggh, aggl, 512, BF_GATW0, 256,  aggh + 256, aggl + 256, 512, BF_GATW1, 256,
      nullptr, nullptr, 0, 0, 0,
      gatb, nullptr, xgh, xgl, NN, 256, 0.5f, 1, 0, 0);

  // ---- RGCN: root -> P3f ; all 4 relation transforms (z-batch) -> xt hi ; agg
  k_gemm_mfma<<<dim3(1, GY, 1), 256, 0, stream>>>(PBh,
      xgh, xgl, 256, BF_WROOT, 256,  nullptr, nullptr, 0, 0, 0,  nullptr, nullptr, 0, 0, 0,
      rgcnb, P3f, nullptr, nullptr, NN, 128, 1.0f, 0, 0, 0);
  k_gemm_mfma<<<dim3(1, GY, NREL), 256, 0, stream>>>(PBh,
      xgh, xgl, 256, BF_WREL, 256,  nullptr, nullptr, 0, 0, 0,  nullptr, nullptr, 0, 0, 0,
      nullptr, nullptr, xth, nullptr, NN, 128, 1.0f, 0, 4096, (long)NN * 128);
  k_rgcn_csr<<<NODEB, 256, 0, stream>>>(xth, rowptr, srcs, ets, cntrel, P3f, p3h, p3l);

  // ---- fusion + L2 normalize
  k_gemm_mfma<<<dim3(1, GY, 1), 256, 0, stream>>>(PBh,
      xsh, xsl, 256, BF_FW0, 256,  xgh, xgl, 256, BF_FW1, 256,  p3h, p3l, 128, BF_FW2, 128,
      fb, out, nullptr, nullptr, NN, 128, 1.0f, 0, 0, 0);
  k_norm<<<(NN + 3) / 4, 256, 0, stream>>>(out);
}